// Round 10
// baseline (1712.356 us; speedup 1.0000x reference)
//
#include <hip/hip_runtime.h>
#include <hip/hip_bf16.h>

constexpr int NB = 4;
constexpr int SEQ = 4096;
constexpr int DIM = 2048;
constexpr int NLAYER = 4;
constexpr int NQH = 16;
constexpr int NKVH = 4;
constexpr int WIN = 512;
constexpr int HDIM = 128;
constexpr int CAPN = 1024;
constexpr int MTOK = NB * CAPN;                 // 4096 latent tokens
constexpr int QKVN = (NQH + 2 * NKVH) * HDIM;  // 3072
constexpr int VOFF = DIM + NKVH * HDIM;        // 2560, start of V cols
constexpr float EPSF = 1.1920928955078125e-07f;

typedef __hip_bfloat16 bf16;
typedef __bf16 b16x8 __attribute__((ext_vector_type(8)));
typedef __bf16 b16x4 __attribute__((ext_vector_type(4)));
typedef float f32x4 __attribute__((ext_vector_type(4)));

#define MFMA16(a, b, c) __builtin_amdgcn_mfma_f32_16x16x32_bf16((a), (b), (c), 0, 0, 0)

__device__ __forceinline__ void gload_lds16(const void* g, void* l) {
  __builtin_amdgcn_global_load_lds((__attribute__((address_space(1))) void*)(void*)g,
                                   (__attribute__((address_space(3))) void*)l, 16, 0, 0);
}

// ---------------- cast f32 -> bf16 ----------------
__global__ __launch_bounds__(256) void cast_kernel(const float* __restrict__ in,
                                                   bf16* __restrict__ out, int n) {
  int i = (blockIdx.x * 256 + threadIdx.x) * 4;
  if (i >= n) return;
  float4 v = *(const float4*)(in + i);
  b16x4 o;
  o[0] = (__bf16)v.x; o[1] = (__bf16)v.y; o[2] = (__bf16)v.z; o[3] = (__bf16)v.w;
  *(b16x4*)((__bf16*)out + i) = o;
}

// ------- cast fc1_w with row interleave: chunk c holds [16 a-rows | 16 gate] -------
__global__ __launch_bounds__(256) void cast_fc1_kernel(const float* __restrict__ in,
                                                       bf16* __restrict__ out) {
  int p = blockIdx.x;
  int chunk = p >> 5, w = p & 31;
  int L = (w < 16) ? (chunk * 16 + w) : (DIM + chunk * 16 + (w - 16));
  const float4* spv = (const float4*)(in + (size_t)L * DIM);
  __bf16* op = (__bf16*)out + (size_t)p * DIM;
  int t = threadIdx.x;
#pragma unroll
  for (int j = 0; j < 2; ++j) {
    float4 v = spv[t + j * 256];
    b16x4 o;
    o[0] = (__bf16)v.x; o[1] = (__bf16)v.y; o[2] = (__bf16)v.z; o[3] = (__bf16)v.w;
    *(b16x4*)(op + (t + j * 256) * 4) = o;
  }
}

// ---------------- router: rw = sigmoid(x @ w^T), all f32 ----------------
__global__ __launch_bounds__(256) void router_kernel(const float* __restrict__ x,
                                                     const float* __restrict__ rwt,
                                                     float* __restrict__ rw_out) {
  int tok = blockIdx.x * 4 + (threadIdx.x >> 6);
  int l = threadIdx.x & 63;
  const float* xr = x + (size_t)tok * DIM;
  float s = 0.f;
  for (int c = l; c < DIM; c += 64) s += xr[c] * rwt[c];
  for (int off = 32; off; off >>= 1) s += __shfl_down(s, off);
  if (l == 0) rw_out[tok] = 1.f / (1.f + expf(-s));
}

// ------- rank count, tiled: block (b, jc, ic) counts chunk-vs-chunk -------
__global__ __launch_bounds__(256) void rankcnt_kernel(const float* __restrict__ rw,
                                                      int* __restrict__ rank) {
  int blk = blockIdx.x;
  int ic = blk & 15, jc = (blk >> 4) & 15, b = blk >> 8;
  __shared__ float4 svi[64];
  int t = threadIdx.x;
  if (t < 64) svi[t] = ((const float4*)(rw + (size_t)b * SEQ + ic * 256))[t];
  __syncthreads();
  int j = jc * 256 + t;
  float vj = rw[(size_t)b * SEQ + j];
  int r = 0;
#pragma unroll 16
  for (int q = 0; q < 64; ++q) {
    float4 v = svi[q];
    int i = ic * 256 + q * 4;
    r += (v.x > vj || (v.x == vj && (i + 0) < j)) ? 1 : 0;
    r += (v.y > vj || (v.y == vj && (i + 1) < j)) ? 1 : 0;
    r += (v.z > vj || (v.z == vj && (i + 2) < j)) ? 1 : 0;
    r += (v.w > vj || (v.w == vj && (i + 3) < j)) ? 1 : 0;
  }
  atomicAdd(&rank[b * SEQ + j], r);
}

// -------- select: compact ascending-index selected; top_w quirk gather;
// also writes the `decisions` output --------
__global__ __launch_bounds__(1024) void select_kernel(const int* __restrict__ rank,
                                                      const float* __restrict__ rw,
                                                      int* __restrict__ idxs,
                                                      float* __restrict__ topw,
                                                      float* __restrict__ dec) {
  int b = blockIdx.x;
  int t = threadIdx.x;
  __shared__ int sr[SEQ];
  __shared__ int scnt[1024];
  for (int i = t; i < SEQ; i += 1024) sr[i] = rank[b * SEQ + i];
  __syncthreads();
  for (int i = t; i < SEQ; i += 1024) dec[(size_t)b * SEQ + i] = (sr[i] < CAPN) ? 1.0f : 0.0f;
  int c = 0;
#pragma unroll
  for (int k = 0; k < 4; ++k) c += (sr[t * 4 + k] < CAPN) ? 1 : 0;
  scnt[t] = c;
  __syncthreads();
  for (int off = 1; off < 1024; off <<= 1) {
    int v = scnt[t];
    int vm = (t >= off) ? scnt[t - off] : 0;
    __syncthreads();
    scnt[t] = v + vm;
    __syncthreads();
  }
  int pos = scnt[t] - c;  // exclusive prefix
  for (int k = 0; k < 4; ++k) {
    int j = t * 4 + k;
    int r = sr[j];
    if (r < CAPN) {
      idxs[b * CAPN + pos] = j;
      topw[b * CAPN + pos] = rw[(size_t)b * SEQ + r];
      pos++;
    }
  }
}

// ---------------- gather selected rows ----------------
__global__ __launch_bounds__(256) void gather_kernel(const float* __restrict__ x,
                                                     const int* __restrict__ idxs,
                                                     float* __restrict__ lat) {
  int tok = blockIdx.x;
  int b = tok >> 10, i = tok & 1023;
  int src = idxs[b * CAPN + i];
  const float4* spv = (const float4*)(x + ((size_t)b * SEQ + src) * DIM);
  float4* dp = (float4*)(lat + (size_t)tok * DIM);
  int t = threadIdx.x;
  dp[t] = spv[t];
  dp[t + 256] = spv[t + 256];
}

// ---------------- RMSNorm (f32 in, bf16 out) ----------------
__global__ __launch_bounds__(256) void rmsnorm_kernel(const float* __restrict__ in,
                                                      const float* __restrict__ w,
                                                      bf16* __restrict__ out) {
  int row = blockIdx.x;
  int t = threadIdx.x;
  const float4* spv = (const float4*)(in + (size_t)row * DIM);
  float4 v0 = spv[t], v1 = spv[t + 256];
  float ss = v0.x * v0.x + v0.y * v0.y + v0.z * v0.z + v0.w * v0.w +
             v1.x * v1.x + v1.y * v1.y + v1.z * v1.z + v1.w * v1.w;
  for (int off = 32; off; off >>= 1) ss += __shfl_down(ss, off);
  __shared__ float red[4];
  if ((t & 63) == 0) red[t >> 6] = ss;
  __syncthreads();
  float total = red[0] + red[1] + red[2] + red[3];
  float sc = rsqrtf(total * (1.0f / DIM) + EPSF);
  const float4* wp = (const float4*)w;
  float4 w0 = wp[t], w1 = wp[t + 256];
  __bf16* op = (__bf16*)out + (size_t)row * DIM;
  b16x4 o0, o1;
  o0[0] = (__bf16)(v0.x * w0.x * sc); o0[1] = (__bf16)(v0.y * w0.y * sc);
  o0[2] = (__bf16)(v0.z * w0.z * sc); o0[3] = (__bf16)(v0.w * w0.w * sc);
  o1[0] = (__bf16)(v1.x * w1.x * sc); o1[1] = (__bf16)(v1.y * w1.y * sc);
  o1[2] = (__bf16)(v1.z * w1.z * sc); o1[3] = (__bf16)(v1.w * w1.w * sc);
  *(b16x4*)(op + t * 4) = o0;
  *(b16x4*)(op + 1024 + t * 4) = o1;
}

// ============ m97-structure GEMM: 128x128 tile, BK=64, single-buffer ============
// 256 thr (4 waves 2x2), LDS 32 KB -> 3 blocks/CU. Mechanism: CROSS-BLOCK
// overlap (m114). MODE: 1 = bf16 + vT side-write; 2 = fused SwiGLU; 3 = f32 add.

__device__ __forceinline__ void stage97(const bf16* g, int K, int kt,
                                        bf16* tile, int tid) {
#pragma unroll
  for (int j = 0; j < 4; ++j) {
    int q = j * 4096 + tid * 16;
    int row = q >> 7;
    int sc = ((tid & 7) ^ (row & 7)) << 3;
    gload_lds16((const __bf16*)g + (size_t)row * K + kt * 64 + sc,
                (char*)tile + q);
  }
}

__device__ __forceinline__ b16x8 frag97(const bf16* buf, int row, int ks, int hi) {
  int co = (ks * 32 + hi * 8) ^ ((row & 7) << 3);
  return *(const b16x8*)((const __bf16*)buf + row * 64 + co);
}

template <int MODE>
__global__ __launch_bounds__(256, 3) void gemm97(const bf16* __restrict__ A,
                                                 const bf16* __restrict__ Bw,
                                                 float* __restrict__ Cf,
                                                 bf16* __restrict__ Cb,
                                                 bf16* __restrict__ vTout,
                                                 int N, int K, int nbn) {
  __shared__ __align__(16) bf16 sA[128 * 64];
  __shared__ __align__(16) bf16 sB[128 * 64];
  const int tid = threadIdx.x;
  const int w = tid >> 6, l = tid & 63;
  const int lo = l & 15, hi = l >> 4;
  const int wr = w >> 1, wc = w & 1;
  const int nwg = gridDim.x;
  int bid = blockIdx.x;
  bid = (bid & 7) * (nwg >> 3) + (bid >> 3);  // T1 XCD swizzle (nwg%8==0)
  const int bm = bid / nbn, bn = bid % nbn;
  const bf16* Ab = A + (size_t)bm * 128 * K;
  const bf16* Bb = Bw + (size_t)bn * 128 * K;
  const int nt = K >> 6;

  f32x4 acc[4][4];
#pragma unroll
  for (int i = 0; i < 4; ++i)
#pragma unroll
    for (int j = 0; j < 4; ++j) acc[i][j] = f32x4{0.f, 0.f, 0.f, 0.f};

  for (int t = 0; t < nt; ++t) {
    stage97(Ab, K, t, sA, tid);
    stage97(Bb, K, t, sB, tid);
    __syncthreads();
#pragma unroll
    for (int ks = 0; ks < 2; ++ks) {
      b16x8 af[4], bfm[4];
#pragma unroll
      for (int mi = 0; mi < 4; ++mi)
        af[mi] = frag97(sA, wr * 64 + mi * 16 + lo, ks, hi);
#pragma unroll
      for (int ni = 0; ni < 4; ++ni)
        bfm[ni] = frag97(sB, wc * 64 + ni * 16 + lo, ks, hi);
#pragma unroll
      for (int mi = 0; mi < 4; ++mi)
#pragma unroll
        for (int ni = 0; ni < 4; ++ni)
          acc[mi][ni] = MFMA16(af[mi], bfm[ni], acc[mi][ni]);
    }
    __syncthreads();
  }

  // epilogue
#pragma unroll
  for (int mi = 0; mi < 4; ++mi) {
    int row0 = bm * 128 + wr * 64 + mi * 16 + hi * 4;
    if constexpr (MODE == 2) {
#pragma unroll
      for (int j2 = 0; j2 < 2; ++j2) {
        int colL = bn * 64 + wc * 32 + j2 * 16 + lo;
#pragma unroll
        for (int r = 0; r < 4; ++r) {
          float a = acc[mi][2 * j2][r];
          float g = acc[mi][2 * j2 + 1][r];
          float s = g / (1.f + __expf(-g));
          Cb[(size_t)(row0 + r) * DIM + colL] = __float2bfloat16(a * s);
        }
      }
    } else {
#pragma unroll
      for (int ni = 0; ni < 4; ++ni) {
        int col = bn * 128 + wc * 64 + ni * 16 + lo;
#pragma unroll
        for (int r = 0; r < 4; ++r) {
          size_t idx = (size_t)(row0 + r) * N + col;
          float v = acc[mi][ni][r];
          if constexpr (MODE == 3) {
            Cf[idx] += v;
          } else {
            bf16 bv = __float2bfloat16(v);
            Cb[idx] = bv;
            if constexpr (MODE == 1) {
              if (col >= VOFF) {
                int cc = col - VOFF;
                int kvh = cc >> 7, d = cc & 127;
                int row = row0 + r;
                int bb = row >> 10, tk = row & 1023;
                vTout[((size_t)(bb * NKVH + kvh) * HDIM + d) * CAPN + tk] = bv;
              }
            }
          }
        }
      }
    }
  }
}

// ------------- GQA attention: 16-row q-chunks for 4 waves/SIMD occupancy.
// grid = NB*NKVH*64 = 1024 blocks (4 blocks/CU, 16 waves/CU). 64-col K-steps,
// diag-first order + wave-uniform defer-max (THR=8), padded P-LDS (stride 72).
// K frags loaded in 2-subtile groups to keep peak VGPR under the 128 cap. -------------
__global__ __launch_bounds__(256, 4) void attn_kernel(const bf16* __restrict__ qkvb,
                                                      const bf16* __restrict__ vT,
                                                      bf16* __restrict__ attb) {
  const int blk = blockIdx.x;
  const int qc = blk & 63;
  const int kvh = (blk >> 6) & 3;
  const int b = blk >> 8;
  const int w = threadIdx.x >> 6, l = threadIdx.x & 63;
  const int lo = l & 15, hi = l >> 4;
  const int h = kvh * 4 + w;
  const float slope = exp2f(-0.5f * (float)(h + 1));
  const float scale = 0.08838834764831845f;  // 1/sqrt(128)
  __shared__ __align__(16) bf16 p_lds[4][16 * 72];  // stride 72 elems (144 B)
  const __bf16* qp = (const __bf16*)qkvb;
  const __bf16* vtp = (const __bf16*)vT + (size_t)(b * NKVH + kvh) * HDIM * CAPN;
  const size_t tb = (size_t)b * CAPN;
  const int i0 = qc * 16;

  b16x8 aq[4];
  {
    const __bf16* qrow = qp + (tb + i0 + lo) * QKVN + h * HDIM + hi * 8;
#pragma unroll
    for (int c = 0; c < 4; ++c) aq[c] = *(const b16x8*)(qrow + c * 32);
  }

  f32x4 acc[8];
#pragma unroll
  for (int d = 0; d < 8; ++d) acc[d] = f32x4{0.f, 0.f, 0.f, 0.f};
  float mrow[4], ssum[4];
#pragma unroll
  for (int r = 0; r < 4; ++r) { mrow[r] = -1e30f; ssum[r] = 0.f; }

  const int Ttile = (i0 + 15) & ~63;
  int Btile = i0 - WIN;
  if (Btile < 0) Btile = 0;
  Btile &= ~63;

  for (int j0 = Ttile; j0 >= Btile; j0 -= 64) {
    // QK^T over 4 jt sub-tiles, K frags in 2 groups (VGPR economy)
    f32x4 s[4];
#pragma unroll
    for (int jtp = 0; jtp < 2; ++jtp) {
      b16x8 kf[2][4];
#pragma unroll
      for (int jt2 = 0; jt2 < 2; ++jt2) {
        const __bf16* krow =
            qp + (tb + j0 + (jtp * 2 + jt2) * 16 + lo) * QKVN + DIM + kvh * HDIM + hi * 8;
#pragma unroll
        for (int c = 0; c < 4; ++c) kf[jt2][c] = *(const b16x8*)(krow + c * 32);
      }
#pragma unroll
      for (int jt2 = 0; jt2 < 2; ++jt2) {
        f32x4 sv = f32x4{0.f, 0.f, 0.f, 0.f};
#pragma unroll
        for (int c = 0; c < 4; ++c) sv = MFMA16(aq[c], kf[jt2][c], sv);
        s[jtp * 2 + jt2] = sv;
      }
    }
    // mask + ALiBi + row-max (in-place); defer-max decision
    float tmv[4];
    int changed = 0;
#pragma unroll
    for (int r = 0; r < 4; ++r) {
      const int i = i0 + hi * 4 + r;
      float tm = -1e30f;
#pragma unroll
      for (int jt = 0; jt < 4; ++jt) {
        int d = i - (j0 + jt * 16 + lo);
        float v = (d >= 0 && d <= 512) ? (s[jt][r] * scale - slope * (float)d) : -1e30f;
        s[jt][r] = v;
        tm = fmaxf(tm, v);
      }
#pragma unroll
      for (int off = 1; off < 16; off <<= 1) tm = fmaxf(tm, __shfl_xor(tm, off));
      tmv[r] = tm;
      changed |= (tm > mrow[r] + 8.0f) ? 1 : 0;
    }
    if (__any(changed)) {  // rare with diag-first order
#pragma unroll
      for (int r = 0; r < 4; ++r) {
        float mnew = fmaxf(mrow[r], tmv[r]);
        float corr = (mrow[r] > -1e29f) ? __expf(mrow[r] - mnew) : 0.f;
        ssum[r] *= corr;
#pragma unroll
        for (int d = 0; d < 8; ++d) acc[d][r] *= corr;
        mrow[r] = mnew;
      }
    }
    // P = exp(s - m), row-sum, write to padded LDS
#pragma unroll
    for (int r = 0; r < 4; ++r) {
      const float m = mrow[r];
      float rs = 0.f;
#pragma unroll
      for (int jt = 0; jt < 4; ++jt) {
        float v = s[jt][r];
        float p = (v > -1e29f) ? __expf(v - m) : 0.f;
        rs += p;
        p_lds[w][(hi * 4 + r) * 72 + jt * 16 + lo] = __float2bfloat16(p);
      }
#pragma unroll
      for (int off = 1; off < 16; off <<= 1) rs += __shfl_xor(rs, off);
      ssum[r] += rs;
    }
    // PV over the 2 k-subtiles of 32
#pragma unroll
    for (int ks2 = 0; ks2 < 2; ++ks2) {
      b16x8 pa = *(const b16x8*)((const __bf16*)p_lds[w] + lo * 72 + ks2 * 32 + hi * 8);
#pragma unroll
      for (int dh = 0; dh < 2; ++dh) {
        b16x8 bv[4];
#pragma unroll
        for (int dd = 0; dd < 4; ++dd) {
          int d = dh * 4 + dd;
          bv[dd] = *(const b16x8*)(vtp + (size_t)(d * 16 + lo) * CAPN + j0 + ks2 * 32 + hi * 8);
        }
#pragma unroll
        for (int dd = 0; dd < 4; ++dd)
          acc[dh * 4 + dd] = MFMA16(pa, bv[dd], acc[dh * 4 + dd]);
      }
    }
  }
#pragma unroll
  for (int d = 0; d < 8; ++d)
#pragma unroll
    for (int r = 0; r < 4; ++r) {
      int row = i0 + hi * 4 + r;
      attb[(tb + row) * DIM + h * HDIM + d * 16 + lo] =
          __float2bfloat16(acc[d][r] / ssum[r]);
    }
}

// ---------------- scale by top_w and scatter into pred ----------------
__global__ __launch_bounds__(256) void scatter_kernel(const float* __restrict__ lat,
                                                      const int* __restrict__ idxs,
                                                      const float* __restrict__ topw,
                                                      float* __restrict__ pred) {
  int tok = blockIdx.x;
  int b = tok >> 10, i = tok & 1023;
  int dst = idxs[b * CAPN + i];
  float wv = topw[b * CAPN + i];
  const float4* spv = (const float4*)(lat + (size_t)tok * DIM);
  float4* dp = (float4*)(pred + ((size_t)b * SEQ + dst) * DIM);
  int t = threadIdx.x;
  float4 v = spv[t];
  v.x *= wv; v.y *= wv; v.z *= wv; v.w *= wv;
  dp[t] = v;
  v = spv[t + 256];
  v.x *= wv; v.y *= wv; v.z *= wv; v.w *= wv;
  dp[t + 256] = v;
}

extern "C" void kernel_launch(void* const* d_in, const int* in_sizes, int n_in,
                              void* d_out, int out_size, void* d_ws, size_t ws_size,
                              hipStream_t stream) {
  const float* x        = (const float*)d_in[0];
  const float* router_w = (const float*)d_in[1];
  const float* norm1_w  = (const float*)d_in[2];
  const float* norm2_w  = (const float*)d_in[3];
  const float* qkv_w    = (const float*)d_in[4];
  const float* proj_w   = (const float*)d_in[5];
  const float* fc1_w    = (const float*)d_in[6];
  const float* fc2_w    = (const float*)d_in[7];

  float* pred   = (float*)d_out;                       // [NB,SEQ,DIM]
  float* rw_out = pred + (size_t)NB * SEQ * DIM;       // [NB,SEQ,1]
  float* dec    = rw_out + (size_t)NB * SEQ;           // [NB,SEQ,1]

  // workspace
  char* ws = (char*)d_ws;
  float* lat  = (float*)ws; ws += (size_t)MTOK * DIM * 4;       // 33.5 MB f32
  bf16* xn    = (bf16*)ws;  ws += (size_t)MTOK * DIM * 2;       // 16.8 MB
  bf16* qkvb  = (bf16*)ws;  ws += (size_t)MTOK * QKVN * 2;      // 25.2 MB
  bf16* attb  = (bf16*)ws;  ws += (size_t)MTOK * DIM * 2;       // 16.8 MB
  int* rank   = (int*)ws;   ws += (size_t)NB * SEQ * 4;
  int* idxs   = (int*)ws;   ws += (size_t)NB * CAPN * 4;
  float* topw = (float*)ws; ws += (size_t)NB * CAPN * 4;

  // scratch inside the pred output region (zeroed only at the very end)
  char* sp = (char*)pred;
  sp += (size_t)MTOK * (2 * DIM) * 2;                          // (hole, unused)
  bf16* wq = (bf16*)sp; sp += (size_t)QKVN * DIM * 2;          // 12.6 MB
  bf16* wp = (bf16*)sp; sp += (size_t)DIM * DIM * 2;           //  8.4 MB
  bf16* w1 = (bf16*)sp; sp += (size_t)(2 * DIM) * DIM * 2;     // 16.8 MB
  bf16* w2 = (bf16*)sp; sp += (size_t)DIM * DIM * 2;           //  8.4 MB
  bf16* vT = (bf16*)sp; sp += (size_t)NB * NKVH * HDIM * CAPN * 2;  // 4.2 MB

  // router + top-k (f32 exact path)
  router_kernel<<<NB * SEQ / 4, 256, 0, stream>>>(x, router_w, rw_out);
  hipMemsetAsync(rank, 0, (size_t)NB * SEQ * 4, stream);
  rankcnt_kernel<<<NB * 256, 256, 0, stream>>>(rw_out, rank);
  select_kernel<<<NB, 1024, 0, stream>>>(rank, rw_out, idxs, topw, dec);
  gather_kernel<<<MTOK, 256, 0, stream>>>(x, idxs, lat);

  for (int l = 0; l < NLAYER; ++l) {
    cast_kernel<<<(QKVN * DIM) / 1024, 256, 0, stream>>>(qkv_w + (size_t)l * QKVN * DIM, wq, QKVN * DIM);
    cast_kernel<<<(DIM * DIM) / 1024, 256, 0, stream>>>(proj_w + (size_t)l * DIM * DIM, wp, DIM * DIM);
    cast_fc1_kernel<<<2 * DIM, 256, 0, stream>>>(fc1_w + (size_t)l * 2 * DIM * DIM, w1);
    cast_kernel<<<(DIM * DIM) / 1024, 256, 0, stream>>>(fc2_w + (size_t)l * DIM * DIM, w2, DIM * DIM);

    rmsnorm_kernel<<<MTOK, 256, 0, stream>>>(lat, norm1_w + (size_t)l * DIM, xn);
    // qkv: M=4096 N=3072 -> grid 32*24 = 768
    gemm97<1><<<(MTOK / 128) * (QKVN / 128), 256, 0, stream>>>(
        xn, wq, nullptr, qkvb, vT, QKVN, DIM, QKVN / 128);
    attn_kernel<<<NB * NKVH * 64, 256, 0, stream>>>(qkvb, vT, attb);
    // proj: residual add into lat, grid 32*16 = 512
    gemm97<3><<<(MTOK / 128) * (DIM / 128), 256, 0, stream>>>(
        attb, wp, lat, nullptr, nullptr, DIM, DIM, DIM / 128);

    rmsnorm_kernel<<<MTOK, 256, 0, stream>>>(lat, norm2_w + (size_t)l * DIM, xn);
    // fc1 + fused SwiGLU: grid 32*32 = 1024, out attb [4096,2048]
    gemm97<2><<<(MTOK / 128) * (2 * DIM / 128), 256, 0, stream>>>(
        xn, w1, nullptr, attb, nullptr, 2 * DIM, DIM, 2 * DIM / 128);
    // fc2: residual add into lat, grid 512
    gemm97<3><<<(MTOK / 128) * (DIM / 128), 256, 0, stream>>>(
        attb, w2, lat, nullptr, nullptr, DIM, DIM, DIM / 128);
  }

  // finalize outputs: zero pred (erases scratch), then scatter lat * top_w
  hipMemsetAsync(pred, 0, (size_t)NB * SEQ * DIM * 4, stream);
  scatter_kernel<<<MTOK, 256, 0, stream>>>(lat, idxs, topw, pred);
}

// Round 11
// 1563.480 us; speedup vs baseline: 1.0952x; 1.0952x over previous
//
#include <hip/hip_runtime.h>
#include <hip/hip_bf16.h>

constexpr int NB = 4;
constexpr int SEQ = 4096;
constexpr int DIM = 2048;
constexpr int NLAYER = 4;
constexpr int NQH = 16;
constexpr int NKVH = 4;
constexpr int WIN = 512;
constexpr int HDIM = 128;
constexpr int CAPN = 1024;
constexpr int MTOK = NB * CAPN;                 // 4096 latent tokens
constexpr int QKVN = (NQH + 2 * NKVH) * HDIM;  // 3072
constexpr int VOFF = DIM + NKVH * HDIM;        // 2560, start of V cols
constexpr float EPSF = 1.1920928955078125e-07f;

typedef __hip_bfloat16 bf16;
typedef __bf16 b16x8 __attribute__((ext_vector_type(8)));
typedef __bf16 b16x4 __attribute__((ext_vector_type(4)));
typedef float f32x4 __attribute__((ext_vector_type(4)));

#define MFMA16(a, b, c) __builtin_amdgcn_mfma_f32_16x16x32_bf16((a), (b), (c), 0, 0, 0)

__device__ __forceinline__ void gload_lds16(const void* g, void* l) {
  __builtin_amdgcn_global_load_lds((__attribute__((address_space(1))) void*)(void*)g,
                                   (__attribute__((address_space(3))) void*)l, 16, 0, 0);
}

// ---------------- cast f32 -> bf16 ----------------
__global__ __launch_bounds__(256) void cast_kernel(const float* __restrict__ in,
                                                   bf16* __restrict__ out, int n) {
  int i = (blockIdx.x * 256 + threadIdx.x) * 4;
  if (i >= n) return;
  float4 v = *(const float4*)(in + i);
  b16x4 o;
  o[0] = (__bf16)v.x; o[1] = (__bf16)v.y; o[2] = (__bf16)v.z; o[3] = (__bf16)v.w;
  *(b16x4*)((__bf16*)out + i) = o;
}

// ------- cast fc1_w with row interleave: chunk c holds [16 a-rows | 16 gate] -------
__global__ __launch_bounds__(256) void cast_fc1_kernel(const float* __restrict__ in,
                                                       bf16* __restrict__ out) {
  int p = blockIdx.x;
  int chunk = p >> 5, w = p & 31;
  int L = (w < 16) ? (chunk * 16 + w) : (DIM + chunk * 16 + (w - 16));
  const float4* spv = (const float4*)(in + (size_t)L * DIM);
  __bf16* op = (__bf16*)out + (size_t)p * DIM;
  int t = threadIdx.x;
#pragma unroll
  for (int j = 0; j < 2; ++j) {
    float4 v = spv[t + j * 256];
    b16x4 o;
    o[0] = (__bf16)v.x; o[1] = (__bf16)v.y; o[2] = (__bf16)v.z; o[3] = (__bf16)v.w;
    *(b16x4*)(op + (t + j * 256) * 4) = o;
  }
}

// ---------------- router: rw = sigmoid(x @ w^T), all f32 ----------------
__global__ __launch_bounds__(256) void router_kernel(const float* __restrict__ x,
                                                     const float* __restrict__ rwt,
                                                     float* __restrict__ rw_out) {
  int tok = blockIdx.x * 4 + (threadIdx.x >> 6);
  int l = threadIdx.x & 63;
  const float* xr = x + (size_t)tok * DIM;
  float s = 0.f;
  for (int c = l; c < DIM; c += 64) s += xr[c] * rwt[c];
  for (int off = 32; off; off >>= 1) s += __shfl_down(s, off);
  if (l == 0) rw_out[tok] = 1.f / (1.f + expf(-s));
}

// ------- rank count, tiled: block (b, jc, ic) counts chunk-vs-chunk -------
__global__ __launch_bounds__(256) void rankcnt_kernel(const float* __restrict__ rw,
                                                      int* __restrict__ rank) {
  int blk = blockIdx.x;
  int ic = blk & 15, jc = (blk >> 4) & 15, b = blk >> 8;
  __shared__ float4 svi[64];
  int t = threadIdx.x;
  if (t < 64) svi[t] = ((const float4*)(rw + (size_t)b * SEQ + ic * 256))[t];
  __syncthreads();
  int j = jc * 256 + t;
  float vj = rw[(size_t)b * SEQ + j];
  int r = 0;
#pragma unroll 16
  for (int q = 0; q < 64; ++q) {
    float4 v = svi[q];
    int i = ic * 256 + q * 4;
    r += (v.x > vj || (v.x == vj && (i + 0) < j)) ? 1 : 0;
    r += (v.y > vj || (v.y == vj && (i + 1) < j)) ? 1 : 0;
    r += (v.z > vj || (v.z == vj && (i + 2) < j)) ? 1 : 0;
    r += (v.w > vj || (v.w == vj && (i + 3) < j)) ? 1 : 0;
  }
  atomicAdd(&rank[b * SEQ + j], r);
}

// -------- select: compact ascending-index selected; top_w quirk gather;
// also writes the `decisions` output --------
__global__ __launch_bounds__(1024) void select_kernel(const int* __restrict__ rank,
                                                      const float* __restrict__ rw,
                                                      int* __restrict__ idxs,
                                                      float* __restrict__ topw,
                                                      float* __restrict__ dec) {
  int b = blockIdx.x;
  int t = threadIdx.x;
  __shared__ int sr[SEQ];
  __shared__ int scnt[1024];
  for (int i = t; i < SEQ; i += 1024) sr[i] = rank[b * SEQ + i];
  __syncthreads();
  for (int i = t; i < SEQ; i += 1024) dec[(size_t)b * SEQ + i] = (sr[i] < CAPN) ? 1.0f : 0.0f;
  int c = 0;
#pragma unroll
  for (int k = 0; k < 4; ++k) c += (sr[t * 4 + k] < CAPN) ? 1 : 0;
  scnt[t] = c;
  __syncthreads();
  for (int off = 1; off < 1024; off <<= 1) {
    int v = scnt[t];
    int vm = (t >= off) ? scnt[t - off] : 0;
    __syncthreads();
    scnt[t] = v + vm;
    __syncthreads();
  }
  int pos = scnt[t] - c;  // exclusive prefix
  for (int k = 0; k < 4; ++k) {
    int j = t * 4 + k;
    int r = sr[j];
    if (r < CAPN) {
      idxs[b * CAPN + pos] = j;
      topw[b * CAPN + pos] = rw[(size_t)b * SEQ + r];
      pos++;
    }
  }
}

// ---------------- gather selected rows ----------------
__global__ __launch_bounds__(256) void gather_kernel(const float* __restrict__ x,
                                                     const int* __restrict__ idxs,
                                                     float* __restrict__ lat) {
  int tok = blockIdx.x;
  int b = tok >> 10, i = tok & 1023;
  int src = idxs[b * CAPN + i];
  const float4* spv = (const float4*)(x + ((size_t)b * SEQ + src) * DIM);
  float4* dp = (float4*)(lat + (size_t)tok * DIM);
  int t = threadIdx.x;
  dp[t] = spv[t];
  dp[t + 256] = spv[t + 256];
}

// ---------------- RMSNorm (f32 in, bf16 out) ----------------
__global__ __launch_bounds__(256) void rmsnorm_kernel(const float* __restrict__ in,
                                                      const float* __restrict__ w,
                                                      bf16* __restrict__ out) {
  int row = blockIdx.x;
  int t = threadIdx.x;
  const float4* spv = (const float4*)(in + (size_t)row * DIM);
  float4 v0 = spv[t], v1 = spv[t + 256];
  float ss = v0.x * v0.x + v0.y * v0.y + v0.z * v0.z + v0.w * v0.w +
             v1.x * v1.x + v1.y * v1.y + v1.z * v1.z + v1.w * v1.w;
  for (int off = 32; off; off >>= 1) ss += __shfl_down(ss, off);
  __shared__ float red[4];
  if ((t & 63) == 0) red[t >> 6] = ss;
  __syncthreads();
  float total = red[0] + red[1] + red[2] + red[3];
  float sc = rsqrtf(total * (1.0f / DIM) + EPSF);
  const float4* wp = (const float4*)w;
  float4 w0 = wp[t], w1 = wp[t + 256];
  __bf16* op = (__bf16*)out + (size_t)row * DIM;
  b16x4 o0, o1;
  o0[0] = (__bf16)(v0.x * w0.x * sc); o0[1] = (__bf16)(v0.y * w0.y * sc);
  o0[2] = (__bf16)(v0.z * w0.z * sc); o0[3] = (__bf16)(v0.w * w0.w * sc);
  o1[0] = (__bf16)(v1.x * w1.x * sc); o1[1] = (__bf16)(v1.y * w1.y * sc);
  o1[2] = (__bf16)(v1.z * w1.z * sc); o1[3] = (__bf16)(v1.w * w1.w * sc);
  *(b16x4*)(op + t * 4) = o0;
  *(b16x4*)(op + 1024 + t * 4) = o1;
}

// ============ m97-structure GEMM: 128x128 tile, BK=64, single-buffer ============
// 256 thr (4 waves 2x2), LDS 32 KB -> 3 blocks/CU. Mechanism: CROSS-BLOCK
// overlap (m114). MODE: 1 = bf16 + vT side-write; 2 = fused SwiGLU; 3 = f32 add.

__device__ __forceinline__ void stage97(const bf16* g, int K, int kt,
                                        bf16* tile, int tid) {
#pragma unroll
  for (int j = 0; j < 4; ++j) {
    int q = j * 4096 + tid * 16;
    int row = q >> 7;
    int sc = ((tid & 7) ^ (row & 7)) << 3;
    gload_lds16((const __bf16*)g + (size_t)row * K + kt * 64 + sc,
                (char*)tile + q);
  }
}

__device__ __forceinline__ b16x8 frag97(const bf16* buf, int row, int ks, int hi) {
  int co = (ks * 32 + hi * 8) ^ ((row & 7) << 3);
  return *(const b16x8*)((const __bf16*)buf + row * 64 + co);
}

template <int MODE>
__global__ __launch_bounds__(256, 3) void gemm97(const bf16* __restrict__ A,
                                                 const bf16* __restrict__ Bw,
                                                 float* __restrict__ Cf,
                                                 bf16* __restrict__ Cb,
                                                 bf16* __restrict__ vTout,
                                                 int N, int K, int nbn) {
  __shared__ __align__(16) bf16 sA[128 * 64];
  __shared__ __align__(16) bf16 sB[128 * 64];
  const int tid = threadIdx.x;
  const int w = tid >> 6, l = tid & 63;
  const int lo = l & 15, hi = l >> 4;
  const int wr = w >> 1, wc = w & 1;
  const int nwg = gridDim.x;
  int bid = blockIdx.x;
  bid = (bid & 7) * (nwg >> 3) + (bid >> 3);  // T1 XCD swizzle (nwg%8==0)
  const int bm = bid / nbn, bn = bid % nbn;
  const bf16* Ab = A + (size_t)bm * 128 * K;
  const bf16* Bb = Bw + (size_t)bn * 128 * K;
  const int nt = K >> 6;

  f32x4 acc[4][4];
#pragma unroll
  for (int i = 0; i < 4; ++i)
#pragma unroll
    for (int j = 0; j < 4; ++j) acc[i][j] = f32x4{0.f, 0.f, 0.f, 0.f};

  for (int t = 0; t < nt; ++t) {
    stage97(Ab, K, t, sA, tid);
    stage97(Bb, K, t, sB, tid);
    __syncthreads();
#pragma unroll
    for (int ks = 0; ks < 2; ++ks) {
      b16x8 af[4], bfm[4];
#pragma unroll
      for (int mi = 0; mi < 4; ++mi)
        af[mi] = frag97(sA, wr * 64 + mi * 16 + lo, ks, hi);
#pragma unroll
      for (int ni = 0; ni < 4; ++ni)
        bfm[ni] = frag97(sB, wc * 64 + ni * 16 + lo, ks, hi);
#pragma unroll
      for (int mi = 0; mi < 4; ++mi)
#pragma unroll
        for (int ni = 0; ni < 4; ++ni)
          acc[mi][ni] = MFMA16(af[mi], bfm[ni], acc[mi][ni]);
    }
    __syncthreads();
  }

  // epilogue
#pragma unroll
  for (int mi = 0; mi < 4; ++mi) {
    int row0 = bm * 128 + wr * 64 + mi * 16 + hi * 4;
    if constexpr (MODE == 2) {
#pragma unroll
      for (int j2 = 0; j2 < 2; ++j2) {
        int colL = bn * 64 + wc * 32 + j2 * 16 + lo;
#pragma unroll
        for (int r = 0; r < 4; ++r) {
          float a = acc[mi][2 * j2][r];
          float g = acc[mi][2 * j2 + 1][r];
          float s = g / (1.f + __expf(-g));
          Cb[(size_t)(row0 + r) * DIM + colL] = __float2bfloat16(a * s);
        }
      }
    } else {
#pragma unroll
      for (int ni = 0; ni < 4; ++ni) {
        int col = bn * 128 + wc * 64 + ni * 16 + lo;
#pragma unroll
        for (int r = 0; r < 4; ++r) {
          size_t idx = (size_t)(row0 + r) * N + col;
          float v = acc[mi][ni][r];
          if constexpr (MODE == 3) {
            Cf[idx] += v;
          } else {
            bf16 bv = __float2bfloat16(v);
            Cb[idx] = bv;
            if constexpr (MODE == 1) {
              if (col >= VOFF) {
                int cc = col - VOFF;
                int kvh = cc >> 7, d = cc & 127;
                int row = row0 + r;
                int bb = row >> 10, tk = row & 1023;
                vTout[((size_t)(bb * NKVH + kvh) * HDIM + d) * CAPN + tk] = bv;
              }
            }
          }
        }
      }
    }
  }
}

// ------------- GQA attention: 32-row q-chunks (R9 structure) + K-tile staged in
// LDS once per block (all 4 waves share the kv-head), double-buffered and
// prefetched one step ahead via global_load_lds. 64-col K-steps, diag-first
// order + wave-uniform defer-max (THR=8), padded P-LDS (stride 72). -------------
__global__ __launch_bounds__(256) void attn_kernel(const bf16* __restrict__ qkvb,
                                                   const bf16* __restrict__ vT,
                                                   bf16* __restrict__ attb) {
  const int blk = blockIdx.x;
  const int qc = blk & 31;
  const int kvh = (blk >> 5) & 3;
  const int b = blk >> 7;
  const int w = threadIdx.x >> 6, l = threadIdx.x & 63;
  const int lo = l & 15, hi = l >> 4;
  const int h = kvh * 4 + w;
  const float slope = exp2f(-0.5f * (float)(h + 1));
  const float scale = 0.08838834764831845f;  // 1/sqrt(128)
  // K tile: 64 rows x 128 d, chunk-swizzled (chunk ^= row&7), double-buffered.
  __shared__ __align__(16) bf16 sK[2][64 * 128];      // 32 KB
  __shared__ __align__(16) bf16 p_lds[4][2][16 * 72]; // 18.4 KB, stride 72
  const __bf16* qp = (const __bf16*)qkvb;
  const __bf16* vtp = (const __bf16*)vT + (size_t)(b * NKVH + kvh) * HDIM * CAPN;
  const size_t tb = (size_t)b * CAPN;
  const int i0b = qc * 32;

  b16x8 aq[2][4];
#pragma unroll
  for (int qt = 0; qt < 2; ++qt) {
    const __bf16* qrow = qp + (tb + i0b + qt * 16 + lo) * QKVN + h * HDIM + hi * 8;
#pragma unroll
    for (int c = 0; c < 4; ++c) aq[qt][c] = *(const b16x8*)(qrow + c * 32);
  }

  f32x4 acc[2][8];
#pragma unroll
  for (int qt = 0; qt < 2; ++qt)
#pragma unroll
    for (int d = 0; d < 8; ++d) acc[qt][d] = f32x4{0.f, 0.f, 0.f, 0.f};
  float mrow[2][4], ssum[2][4];
#pragma unroll
  for (int qt = 0; qt < 2; ++qt)
#pragma unroll
    for (int r = 0; r < 4; ++r) { mrow[qt][r] = -1e30f; ssum[qt][r] = 0.f; }

  const int Ttile = (i0b + 31) & ~63;
  int Btile = i0b - WIN;
  if (Btile < 0) Btile = 0;
  Btile &= ~63;

  // stage K tile for j0 into sK[bufi]: linear dest, source chunk pre-swizzled
  auto stageK = [&](int j0, int bufi) {
    const __bf16* gb = qp + (tb + j0) * QKVN + DIM + kvh * HDIM;
#pragma unroll
    for (int jj = 0; jj < 4; ++jj) {
      int q = jj * 4096 + threadIdx.x * 16;  // byte offset in 16KB tile
      int rowd = q >> 8;                     // 256 B per row (128 bf16)
      int ch = (q >> 4) & 15;                // 16B chunk within row
      int chs = ch ^ (rowd & 7);             // inverse-swizzled source chunk
      gload_lds16(gb + (size_t)rowd * QKVN + chs * 8, (char*)sK[bufi] + q);
    }
  };

  stageK(Ttile, 0);
  asm volatile("s_waitcnt vmcnt(0)" ::: "memory");
  __builtin_amdgcn_sched_barrier(0);
  __syncthreads();

  int cur = 0;
  for (int j0 = Ttile; j0 >= Btile; j0 -= 64) {
    const bool more = (j0 - 64) >= Btile;
    if (more) stageK(j0 - 64, cur ^ 1);  // async prefetch; hidden under this iter
    const __bf16* kb = (const __bf16*)sK[cur];
    // QK^T: K frags from LDS (swizzled chunks -> 2-way banks, free)
    f32x4 s[2][4];
#pragma unroll
    for (int jtp = 0; jtp < 2; ++jtp) {
      b16x8 kf[2][4];
#pragma unroll
      for (int jt2 = 0; jt2 < 2; ++jt2) {
        int rr = (jtp * 2 + jt2) * 16 + lo;
#pragma unroll
        for (int c = 0; c < 4; ++c)
          kf[jt2][c] = *(const b16x8*)(kb + rr * 128 + (((c * 4 + hi) ^ (rr & 7)) << 3));
      }
#pragma unroll
      for (int qt = 0; qt < 2; ++qt)
#pragma unroll
        for (int jt2 = 0; jt2 < 2; ++jt2) {
          f32x4 sv = f32x4{0.f, 0.f, 0.f, 0.f};
#pragma unroll
          for (int c = 0; c < 4; ++c) sv = MFMA16(aq[qt][c], kf[jt2][c], sv);
          s[qt][jtp * 2 + jt2] = sv;
        }
    }
    // mask + ALiBi + row-max (in-place into s); defer-max decision
    float tmv[2][4];
    int changed = 0;
#pragma unroll
    for (int qt = 0; qt < 2; ++qt) {
#pragma unroll
      for (int r = 0; r < 4; ++r) {
        const int i = i0b + qt * 16 + hi * 4 + r;
        float tm = -1e30f;
#pragma unroll
        for (int jt = 0; jt < 4; ++jt) {
          int d = i - (j0 + jt * 16 + lo);
          float v = (d >= 0 && d <= 512) ? (s[qt][jt][r] * scale - slope * (float)d)
                                         : -1e30f;
          s[qt][jt][r] = v;
          tm = fmaxf(tm, v);
        }
#pragma unroll
        for (int off = 1; off < 16; off <<= 1) tm = fmaxf(tm, __shfl_xor(tm, off));
        tmv[qt][r] = tm;
        changed |= (tm > mrow[qt][r] + 8.0f) ? 1 : 0;
      }
    }
    if (__any(changed)) {  // rare with diag-first order
#pragma unroll
      for (int qt = 0; qt < 2; ++qt)
#pragma unroll
        for (int r = 0; r < 4; ++r) {
          float mnew = fmaxf(mrow[qt][r], tmv[qt][r]);
          float corr = (mrow[qt][r] > -1e29f) ? __expf(mrow[qt][r] - mnew) : 0.f;
          ssum[qt][r] *= corr;
#pragma unroll
          for (int d = 0; d < 8; ++d) acc[qt][d][r] *= corr;
          mrow[qt][r] = mnew;
        }
    }
    // P = exp(s - m), row-sum, write to padded LDS
#pragma unroll
    for (int qt = 0; qt < 2; ++qt) {
#pragma unroll
      for (int r = 0; r < 4; ++r) {
        const float m = mrow[qt][r];
        float rs = 0.f;
#pragma unroll
        for (int jt = 0; jt < 4; ++jt) {
          float v = s[qt][jt][r];
          float p = (v > -1e29f) ? __expf(v - m) : 0.f;
          rs += p;
          p_lds[w][qt][(hi * 4 + r) * 72 + jt * 16 + lo] = __float2bfloat16(p);
        }
#pragma unroll
        for (int off = 1; off < 16; off <<= 1) rs += __shfl_xor(rs, off);
        ssum[qt][r] += rs;
      }
    }
    // PV over the 2 k-subtiles of 32 (V from vT, contiguous)
#pragma unroll
    for (int ks2 = 0; ks2 < 2; ++ks2) {
      b16x8 pa[2];
      pa[0] = *(const b16x8*)((const __bf16*)p_lds[w][0] + lo * 72 + ks2 * 32 + hi * 8);
      pa[1] = *(const b16x8*)((const __bf16*)p_lds[w][1] + lo * 72 + ks2 * 32 + hi * 8);
#pragma unroll
      for (int dh = 0; dh < 2; ++dh) {
        b16x8 bv[4];
#pragma unroll
        for (int dd = 0; dd < 4; ++dd) {
          int d = dh * 4 + dd;
          bv[dd] = *(const b16x8*)(vtp + (size_t)(d * 16 + lo) * CAPN + j0 + ks2 * 32 + hi * 8);
        }
#pragma unroll
        for (int qt = 0; qt < 2; ++qt)
#pragma unroll
          for (int dd = 0; dd < 4; ++dd)
            acc[qt][dh * 4 + dd] = MFMA16(pa[qt], bv[dd], acc[qt][dh * 4 + dd]);
      }
    }
    if (more) {
      // prefetch complete + all waves done reading cur before it is overwritten
      asm volatile("s_waitcnt vmcnt(0)" ::: "memory");
      __builtin_amdgcn_sched_barrier(0);
      __syncthreads();
      cur ^= 1;
    }
  }
#pragma unroll
  for (int qt = 0; qt < 2; ++qt)
#pragma unroll
    for (int d = 0; d < 8; ++d)
#pragma unroll
      for (int r = 0; r < 4; ++r) {
        int row = i0b + qt * 16 + hi * 4 + r;
        attb[(tb + row) * DIM + h * HDIM + d * 16 + lo] =
            __float2bfloat16(acc[qt][d][r] / ssum[qt][r]);
      }
}

// ---------------- scale by top_w and scatter into pred ----------------
__global__ __launch_bounds__(256) void scatter_kernel(const float* __restrict__ lat,
                                                      const int* __restrict__ idxs,
                                                      const float* __restrict__ topw,
                                                      float* __restrict__ pred) {
  int tok = blockIdx.x;
  int b = tok >> 10, i = tok & 1023;
  int dst = idxs[b * CAPN + i];
  float wv = topw[b * CAPN + i];
  const float4* spv = (const float4*)(lat + (size_t)tok * DIM);
  float4* dp = (float4*)(pred + ((size_t)b * SEQ + dst) * DIM);
  int t = threadIdx.x;
  float4 v = spv[t];
  v.x *= wv; v.y *= wv; v.z *= wv; v.w *= wv;
  dp[t] = v;
  v = spv[t + 256];
  v.x *= wv; v.y *= wv; v.z *= wv; v.w *= wv;
  dp[t + 256] = v;
}

extern "C" void kernel_launch(void* const* d_in, const int* in_sizes, int n_in,
                              void* d_out, int out_size, void* d_ws, size_t ws_size,
                              hipStream_t stream) {
  const float* x        = (const float*)d_in[0];
  const float* router_w = (const float*)d_in[1];
  const float* norm1_w  = (const float*)d_in[2];
  const float* norm2_w  = (const float*)d_in[3];
  const float* qkv_w    = (const float*)d_in[4];
  const float* proj_w   = (const float*)d_in[5];
  const float* fc1_w    = (const float*)d_in[6];
  const float* fc2_w    = (const float*)d_in[7];

  float* pred   = (float*)d_out;                       // [NB,SEQ,DIM]
  float* rw_out = pred + (size_t)NB * SEQ * DIM;       // [NB,SEQ,1]
  float* dec    = rw_out + (size_t)NB * SEQ;           // [NB,SEQ,1]

  // workspace
  char* ws = (char*)d_ws;
  float* lat  = (float*)ws; ws += (size_t)MTOK * DIM * 4;       // 33.5 MB f32
  bf16* xn    = (bf16*)ws;  ws += (size_t)MTOK * DIM * 2;       // 16.8 MB
  bf16* qkvb  = (bf16*)ws;  ws += (size_t)MTOK * QKVN * 2;      // 25.2 MB
  bf16* attb  = (bf16*)ws;  ws += (size_t)MTOK * DIM * 2;       // 16.8 MB
  int* rank   = (int*)ws;   ws += (size_t)NB * SEQ * 4;
  int* idxs   = (int*)ws;   ws += (size_t)NB * CAPN * 4;
  float* topw = (float*)ws; ws += (size_t)NB * CAPN * 4;

  // scratch inside the pred output region (zeroed only at the very end)
  char* sp = (char*)pred;
  sp += (size_t)MTOK * (2 * DIM) * 2;                          // (hole, unused)
  bf16* wq = (bf16*)sp; sp += (size_t)QKVN * DIM * 2;          // 12.6 MB
  bf16* wp = (bf16*)sp; sp += (size_t)DIM * DIM * 2;           //  8.4 MB
  bf16* w1 = (bf16*)sp; sp += (size_t)(2 * DIM) * DIM * 2;     // 16.8 MB
  bf16* w2 = (bf16*)sp; sp += (size_t)DIM * DIM * 2;           //  8.4 MB
  bf16* vT = (bf16*)sp; sp += (size_t)NB * NKVH * HDIM * CAPN * 2;  // 4.2 MB

  // router + top-k (f32 exact path)
  router_kernel<<<NB * SEQ / 4, 256, 0, stream>>>(x, router_w, rw_out);
  hipMemsetAsync(rank, 0, (size_t)NB * SEQ * 4, stream);
  rankcnt_kernel<<<NB * 256, 256, 0, stream>>>(rw_out, rank);
  select_kernel<<<NB, 1024, 0, stream>>>(rank, rw_out, idxs, topw, dec);
  gather_kernel<<<MTOK, 256, 0, stream>>>(x, idxs, lat);

  for (int l = 0; l < NLAYER; ++l) {
    cast_kernel<<<(QKVN * DIM) / 1024, 256, 0, stream>>>(qkv_w + (size_t)l * QKVN * DIM, wq, QKVN * DIM);
    cast_kernel<<<(DIM * DIM) / 1024, 256, 0, stream>>>(proj_w + (size_t)l * DIM * DIM, wp, DIM * DIM);
    cast_fc1_kernel<<<2 * DIM, 256, 0, stream>>>(fc1_w + (size_t)l * 2 * DIM * DIM, w1);
    cast_kernel<<<(DIM * DIM) / 1024, 256, 0, stream>>>(fc2_w + (size_t)l * DIM * DIM, w2, DIM * DIM);

    rmsnorm_kernel<<<MTOK, 256, 0, stream>>>(lat, norm1_w + (size_t)l * DIM, xn);
    // qkv: M=4096 N=3072 -> grid 32*24 = 768
    gemm97<1><<<(MTOK / 128) * (QKVN / 128), 256, 0, stream>>>(
        xn, wq, nullptr, qkvb, vT, QKVN, DIM, QKVN / 128);
    attn_kernel<<<NB * NKVH * 32, 256, 0, stream>>>(qkvb, vT, attb);
    // proj: residual add into lat, grid 32*16 = 512
    gemm97<3><<<(MTOK / 128) * (DIM / 128), 256, 0, stream>>>(
        attb, wp, lat, nullptr, nullptr, DIM, DIM, DIM / 128);

    rmsnorm_kernel<<<MTOK, 256, 0, stream>>>(lat, norm2_w + (size_t)l * DIM, xn);
    // fc1 + fused SwiGLU: grid 32*32 = 1024, out attb [4096,2048]
    gemm97<2><<<(MTOK / 128) * (2 * DIM / 128), 256, 0, stream>>>(
        xn, w1, nullptr, attb, nullptr, 2 * DIM, DIM, 2 * DIM / 128);
    // fc2: residual add into lat, grid 512
    gemm97<3><<<(MTOK / 128) * (DIM / 128), 256, 0, stream>>>(
        attb, w2, lat, nullptr, nullptr, DIM, DIM, DIM / 128);
  }

  // finalize outputs: zero pred (erases scratch), then scatter lat * top_w
  hipMemsetAsync(pred, 0, (size_t)NB * SEQ * DIM * 4, stream);
  scatter_kernel<<<MTOK, 256, 0, stream>>>(lat, idxs, topw, pred);
}

// Round 12
// 1499.763 us; speedup vs baseline: 1.1418x; 1.0425x over previous
//
#include <hip/hip_runtime.h>
#include <hip/hip_bf16.h>

constexpr int NB = 4;
constexpr int SEQ = 4096;
constexpr int DIM = 2048;
constexpr int NLAYER = 4;
constexpr int NQH = 16;
constexpr int NKVH = 4;
constexpr int WIN = 512;
constexpr int HDIM = 128;
constexpr int CAPN = 1024;
constexpr int MTOK = NB * CAPN;                 // 4096 latent tokens
constexpr int QKVN = (NQH + 2 * NKVH) * HDIM;  // 3072
constexpr int VOFF = DIM + NKVH * HDIM;        // 2560, start of V cols
constexpr float EPSF = 1.1920928955078125e-07f;

typedef __hip_bfloat16 bf16;
typedef __bf16 b16x8 __attribute__((ext_vector_type(8)));
typedef __bf16 b16x4 __attribute__((ext_vector_type(4)));
typedef float f32x4 __attribute__((ext_vector_type(4)));

#define MFMA16(a, b, c) __builtin_amdgcn_mfma_f32_16x16x32_bf16((a), (b), (c), 0, 0, 0)

__device__ __forceinline__ void gload_lds16(const void* g, void* l) {
  __builtin_amdgcn_global_load_lds((__attribute__((address_space(1))) void*)(void*)g,
                                   (__attribute__((address_space(3))) void*)l, 16, 0, 0);
}

// ---------------- cast f32 -> bf16 ----------------
__global__ __launch_bounds__(256) void cast_kernel(const float* __restrict__ in,
                                                   bf16* __restrict__ out, int n) {
  int i = (blockIdx.x * 256 + threadIdx.x) * 4;
  if (i >= n) return;
  float4 v = *(const float4*)(in + i);
  b16x4 o;
  o[0] = (__bf16)v.x; o[1] = (__bf16)v.y; o[2] = (__bf16)v.z; o[3] = (__bf16)v.w;
  *(b16x4*)((__bf16*)out + i) = o;
}

// ------- cast fc1_w with row interleave: chunk c holds [16 a-rows | 16 gate] -------
__global__ __launch_bounds__(256) void cast_fc1_kernel(const float* __restrict__ in,
                                                       bf16* __restrict__ out) {
  int p = blockIdx.x;
  int chunk = p >> 5, w = p & 31;
  int L = (w < 16) ? (chunk * 16 + w) : (DIM + chunk * 16 + (w - 16));
  const float4* spv = (const float4*)(in + (size_t)L * DIM);
  __bf16* op = (__bf16*)out + (size_t)p * DIM;
  int t = threadIdx.x;
#pragma unroll
  for (int j = 0; j < 2; ++j) {
    float4 v = spv[t + j * 256];
    b16x4 o;
    o[0] = (__bf16)v.x; o[1] = (__bf16)v.y; o[2] = (__bf16)v.z; o[3] = (__bf16)v.w;
    *(b16x4*)(op + (t + j * 256) * 4) = o;
  }
}

// ---------------- router: rw = sigmoid(x @ w^T), all f32 ----------------
__global__ __launch_bounds__(256) void router_kernel(const float* __restrict__ x,
                                                     const float* __restrict__ rwt,
                                                     float* __restrict__ rw_out) {
  int tok = blockIdx.x * 4 + (threadIdx.x >> 6);
  int l = threadIdx.x & 63;
  const float* xr = x + (size_t)tok * DIM;
  float s = 0.f;
  for (int c = l; c < DIM; c += 64) s += xr[c] * rwt[c];
  for (int off = 32; off; off >>= 1) s += __shfl_down(s, off);
  if (l == 0) rw_out[tok] = 1.f / (1.f + expf(-s));
}

// ------- rank count, tiled: block (b, jc, ic) counts chunk-vs-chunk -------
__global__ __launch_bounds__(256) void rankcnt_kernel(const float* __restrict__ rw,
                                                      int* __restrict__ rank) {
  int blk = blockIdx.x;
  int ic = blk & 15, jc = (blk >> 4) & 15, b = blk >> 8;
  __shared__ float4 svi[64];
  int t = threadIdx.x;
  if (t < 64) svi[t] = ((const float4*)(rw + (size_t)b * SEQ + ic * 256))[t];
  __syncthreads();
  int j = jc * 256 + t;
  float vj = rw[(size_t)b * SEQ + j];
  int r = 0;
#pragma unroll 16
  for (int q = 0; q < 64; ++q) {
    float4 v = svi[q];
    int i = ic * 256 + q * 4;
    r += (v.x > vj || (v.x == vj && (i + 0) < j)) ? 1 : 0;
    r += (v.y > vj || (v.y == vj && (i + 1) < j)) ? 1 : 0;
    r += (v.z > vj || (v.z == vj && (i + 2) < j)) ? 1 : 0;
    r += (v.w > vj || (v.w == vj && (i + 3) < j)) ? 1 : 0;
  }
  atomicAdd(&rank[b * SEQ + j], r);
}

// -------- select: compact ascending-index selected; top_w quirk gather;
// also writes the `decisions` output --------
__global__ __launch_bounds__(1024) void select_kernel(const int* __restrict__ rank,
                                                      const float* __restrict__ rw,
                                                      int* __restrict__ idxs,
                                                      float* __restrict__ topw,
                                                      float* __restrict__ dec) {
  int b = blockIdx.x;
  int t = threadIdx.x;
  __shared__ int sr[SEQ];
  __shared__ int scnt[1024];
  for (int i = t; i < SEQ; i += 1024) sr[i] = rank[b * SEQ + i];
  __syncthreads();
  for (int i = t; i < SEQ; i += 1024) dec[(size_t)b * SEQ + i] = (sr[i] < CAPN) ? 1.0f : 0.0f;
  int c = 0;
#pragma unroll
  for (int k = 0; k < 4; ++k) c += (sr[t * 4 + k] < CAPN) ? 1 : 0;
  scnt[t] = c;
  __syncthreads();
  for (int off = 1; off < 1024; off <<= 1) {
    int v = scnt[t];
    int vm = (t >= off) ? scnt[t - off] : 0;
    __syncthreads();
    scnt[t] = v + vm;
    __syncthreads();
  }
  int pos = scnt[t] - c;  // exclusive prefix
  for (int k = 0; k < 4; ++k) {
    int j = t * 4 + k;
    int r = sr[j];
    if (r < CAPN) {
      idxs[b * CAPN + pos] = j;
      topw[b * CAPN + pos] = rw[(size_t)b * SEQ + r];
      pos++;
    }
  }
}

// ---------------- gather selected rows ----------------
__global__ __launch_bounds__(256) void gather_kernel(const float* __restrict__ x,
                                                     const int* __restrict__ idxs,
                                                     float* __restrict__ lat) {
  int tok = blockIdx.x;
  int b = tok >> 10, i = tok & 1023;
  int src = idxs[b * CAPN + i];
  const float4* spv = (const float4*)(x + ((size_t)b * SEQ + src) * DIM);
  float4* dp = (float4*)(lat + (size_t)tok * DIM);
  int t = threadIdx.x;
  dp[t] = spv[t];
  dp[t + 256] = spv[t + 256];
}

// ---------------- RMSNorm (f32 in, bf16 out) ----------------
__global__ __launch_bounds__(256) void rmsnorm_kernel(const float* __restrict__ in,
                                                      const float* __restrict__ w,
                                                      bf16* __restrict__ out) {
  int row = blockIdx.x;
  int t = threadIdx.x;
  const float4* spv = (const float4*)(in + (size_t)row * DIM);
  float4 v0 = spv[t], v1 = spv[t + 256];
  float ss = v0.x * v0.x + v0.y * v0.y + v0.z * v0.z + v0.w * v0.w +
             v1.x * v1.x + v1.y * v1.y + v1.z * v1.z + v1.w * v1.w;
  for (int off = 32; off; off >>= 1) ss += __shfl_down(ss, off);
  __shared__ float red[4];
  if ((t & 63) == 0) red[t >> 6] = ss;
  __syncthreads();
  float total = red[0] + red[1] + red[2] + red[3];
  float sc = rsqrtf(total * (1.0f / DIM) + EPSF);
  const float4* wp = (const float4*)w;
  float4 w0 = wp[t], w1 = wp[t + 256];
  __bf16* op = (__bf16*)out + (size_t)row * DIM;
  b16x4 o0, o1;
  o0[0] = (__bf16)(v0.x * w0.x * sc); o0[1] = (__bf16)(v0.y * w0.y * sc);
  o0[2] = (__bf16)(v0.z * w0.z * sc); o0[3] = (__bf16)(v0.w * w0.w * sc);
  o1[0] = (__bf16)(v1.x * w1.x * sc); o1[1] = (__bf16)(v1.y * w1.y * sc);
  o1[2] = (__bf16)(v1.z * w1.z * sc); o1[3] = (__bf16)(v1.w * w1.w * sc);
  *(b16x4*)(op + t * 4) = o0;
  *(b16x4*)(op + 1024 + t * 4) = o1;
}

// ============ m97-structure GEMM: 128x128 tile, BK=64, single-buffer ============
// 256 thr (4 waves 2x2), LDS 32 KB -> 3 blocks/CU. Mechanism: CROSS-BLOCK
// overlap (m114). MODE: 1 = bf16 + vT side-write; 2 = fused SwiGLU; 3 = f32 add.

__device__ __forceinline__ void stage97(const bf16* g, int K, int kt,
                                        bf16* tile, int tid) {
#pragma unroll
  for (int j = 0; j < 4; ++j) {
    int q = j * 4096 + tid * 16;
    int row = q >> 7;
    int sc = ((tid & 7) ^ (row & 7)) << 3;
    gload_lds16((const __bf16*)g + (size_t)row * K + kt * 64 + sc,
                (char*)tile + q);
  }
}

__device__ __forceinline__ b16x8 frag97(const bf16* buf, int row, int ks, int hi) {
  int co = (ks * 32 + hi * 8) ^ ((row & 7) << 3);
  return *(const b16x8*)((const __bf16*)buf + row * 64 + co);
}

template <int MODE>
__global__ __launch_bounds__(256, 3) void gemm97(const bf16* __restrict__ A,
                                                 const bf16* __restrict__ Bw,
                                                 float* __restrict__ Cf,
                                                 bf16* __restrict__ Cb,
                                                 bf16* __restrict__ vTout,
                                                 int N, int K, int nbn) {
  __shared__ __align__(16) bf16 sA[128 * 64];
  __shared__ __align__(16) bf16 sB[128 * 64];
  const int tid = threadIdx.x;
  const int w = tid >> 6, l = tid & 63;
  const int lo = l & 15, hi = l >> 4;
  const int wr = w >> 1, wc = w & 1;
  const int nwg = gridDim.x;
  int bid = blockIdx.x;
  bid = (bid & 7) * (nwg >> 3) + (bid >> 3);  // T1 XCD swizzle (nwg%8==0)
  const int bm = bid / nbn, bn = bid % nbn;
  const bf16* Ab = A + (size_t)bm * 128 * K;
  const bf16* Bb = Bw + (size_t)bn * 128 * K;
  const int nt = K >> 6;

  f32x4 acc[4][4];
#pragma unroll
  for (int i = 0; i < 4; ++i)
#pragma unroll
    for (int j = 0; j < 4; ++j) acc[i][j] = f32x4{0.f, 0.f, 0.f, 0.f};

  for (int t = 0; t < nt; ++t) {
    stage97(Ab, K, t, sA, tid);
    stage97(Bb, K, t, sB, tid);
    __syncthreads();
#pragma unroll
    for (int ks = 0; ks < 2; ++ks) {
      b16x8 af[4], bfm[4];
#pragma unroll
      for (int mi = 0; mi < 4; ++mi)
        af[mi] = frag97(sA, wr * 64 + mi * 16 + lo, ks, hi);
#pragma unroll
      for (int ni = 0; ni < 4; ++ni)
        bfm[ni] = frag97(sB, wc * 64 + ni * 16 + lo, ks, hi);
#pragma unroll
      for (int mi = 0; mi < 4; ++mi)
#pragma unroll
        for (int ni = 0; ni < 4; ++ni)
          acc[mi][ni] = MFMA16(af[mi], bfm[ni], acc[mi][ni]);
    }
    __syncthreads();
  }

  // epilogue
#pragma unroll
  for (int mi = 0; mi < 4; ++mi) {
    int row0 = bm * 128 + wr * 64 + mi * 16 + hi * 4;
    if constexpr (MODE == 2) {
#pragma unroll
      for (int j2 = 0; j2 < 2; ++j2) {
        int colL = bn * 64 + wc * 32 + j2 * 16 + lo;
#pragma unroll
        for (int r = 0; r < 4; ++r) {
          float a = acc[mi][2 * j2][r];
          float g = acc[mi][2 * j2 + 1][r];
          float s = g / (1.f + __expf(-g));
          Cb[(size_t)(row0 + r) * DIM + colL] = __float2bfloat16(a * s);
        }
      }
    } else {
#pragma unroll
      for (int ni = 0; ni < 4; ++ni) {
        int col = bn * 128 + wc * 64 + ni * 16 + lo;
#pragma unroll
        for (int r = 0; r < 4; ++r) {
          size_t idx = (size_t)(row0 + r) * N + col;
          float v = acc[mi][ni][r];
          if constexpr (MODE == 3) {
            Cf[idx] += v;
          } else {
            bf16 bv = __float2bfloat16(v);
            Cb[idx] = bv;
            if constexpr (MODE == 1) {
              if (col >= VOFF) {
                int cc = col - VOFF;
                int kvh = cc >> 7, d = cc & 127;
                int row = row0 + r;
                int bb = row >> 10, tk = row & 1023;
                vTout[((size_t)(bb * NKVH + kvh) * HDIM + d) * CAPN + tk] = bv;
              }
            }
          }
        }
      }
    }
  }
}

// ------------- GQA attention (R9 structure): 32-row q-chunks, direct-global K
// (L1 serves cross-wave re-reads), 64-col K-steps, diag-first order.
// NEW: (a) row-sum via ones-MFMA accumulator accs (replaces shfl-sum chain),
// rescaled alongside acc in the rare branch; (b) defer-max check is per-lane
// compare + __any ballot (no shfl); full max-reduce only in the rare branch.
// First tile triggers the branch naturally (valid v > -1e30+8). -------------
__global__ __launch_bounds__(256) void attn_kernel(const bf16* __restrict__ qkvb,
                                                   const bf16* __restrict__ vT,
                                                   bf16* __restrict__ attb) {
  const int blk = blockIdx.x;
  const int qc = blk & 31;
  const int kvh = (blk >> 5) & 3;
  const int b = blk >> 7;
  const int w = threadIdx.x >> 6, l = threadIdx.x & 63;
  const int lo = l & 15, hi = l >> 4;
  const int h = kvh * 4 + w;
  const float slope = exp2f(-0.5f * (float)(h + 1));
  const float scale = 0.08838834764831845f;  // 1/sqrt(128)
  __shared__ __align__(16) bf16 p_lds[4][2][16 * 72];  // stride 72 elems (144 B)
  const __bf16* qp = (const __bf16*)qkvb;
  const __bf16* vtp = (const __bf16*)vT + (size_t)(b * NKVH + kvh) * HDIM * CAPN;
  const size_t tb = (size_t)b * CAPN;
  const int i0b = qc * 32;

  b16x8 aq[2][4];
#pragma unroll
  for (int qt = 0; qt < 2; ++qt) {
    const __bf16* qrow = qp + (tb + i0b + qt * 16 + lo) * QKVN + h * HDIM + hi * 8;
#pragma unroll
    for (int c = 0; c < 4; ++c) aq[qt][c] = *(const b16x8*)(qrow + c * 32);
  }

  b16x8 ONES;
#pragma unroll
  for (int j = 0; j < 8; ++j) ONES[j] = (__bf16)1.0f;

  f32x4 acc[2][8];
  f32x4 accs[2];  // row-sum accumulators (via ones-MFMA)
#pragma unroll
  for (int qt = 0; qt < 2; ++qt) {
#pragma unroll
    for (int d = 0; d < 8; ++d) acc[qt][d] = f32x4{0.f, 0.f, 0.f, 0.f};
    accs[qt] = f32x4{0.f, 0.f, 0.f, 0.f};
  }
  float mrow[2][4];
#pragma unroll
  for (int qt = 0; qt < 2; ++qt)
#pragma unroll
    for (int r = 0; r < 4; ++r) mrow[qt][r] = -1e30f;

  const int Ttile = (i0b + 31) & ~63;
  int Btile = i0b - WIN;
  if (Btile < 0) Btile = 0;
  Btile &= ~63;

  for (int j0 = Ttile; j0 >= Btile; j0 -= 64) {
    // QK^T over 4 jt sub-tiles, K frags direct from global (L1-hot), 2 groups
    f32x4 s[2][4];
#pragma unroll
    for (int jtp = 0; jtp < 2; ++jtp) {
      b16x8 kf[2][4];
#pragma unroll
      for (int jt2 = 0; jt2 < 2; ++jt2) {
        const __bf16* krow =
            qp + (tb + j0 + (jtp * 2 + jt2) * 16 + lo) * QKVN + DIM + kvh * HDIM + hi * 8;
#pragma unroll
        for (int c = 0; c < 4; ++c) kf[jt2][c] = *(const b16x8*)(krow + c * 32);
      }
#pragma unroll
      for (int qt = 0; qt < 2; ++qt)
#pragma unroll
        for (int jt2 = 0; jt2 < 2; ++jt2) {
          f32x4 sv = f32x4{0.f, 0.f, 0.f, 0.f};
#pragma unroll
          for (int c = 0; c < 4; ++c) sv = MFMA16(aq[qt][c], kf[jt2][c], sv);
          s[qt][jtp * 2 + jt2] = sv;
        }
    }
    // mask + ALiBi in place; per-lane defer-max check (no shfl on fast path)
    int flag = 0;
#pragma unroll
    for (int qt = 0; qt < 2; ++qt) {
#pragma unroll
      for (int r = 0; r < 4; ++r) {
        const int i = i0b + qt * 16 + hi * 4 + r;
        const float thr = mrow[qt][r] + 8.0f;
#pragma unroll
        for (int jt = 0; jt < 4; ++jt) {
          int d = i - (j0 + jt * 16 + lo);
          float v = (d >= 0 && d <= 512) ? (s[qt][jt][r] * scale - slope * (float)d)
                                         : -1e30f;
          s[qt][jt][r] = v;
          flag |= (v > thr) ? 1 : 0;
        }
      }
    }
    if (__any(flag)) {  // rare (first tile + occasional max growth)
#pragma unroll
      for (int qt = 0; qt < 2; ++qt)
#pragma unroll
        for (int r = 0; r < 4; ++r) {
          float tm = -1e30f;
#pragma unroll
          for (int jt = 0; jt < 4; ++jt) tm = fmaxf(tm, s[qt][jt][r]);
#pragma unroll
          for (int off = 1; off < 16; off <<= 1) tm = fmaxf(tm, __shfl_xor(tm, off));
          float mnew = fmaxf(mrow[qt][r], tm);
          float corr = (mrow[qt][r] > -1e29f) ? __expf(mrow[qt][r] - mnew) : 0.f;
          accs[qt][r] *= corr;
#pragma unroll
          for (int d = 0; d < 8; ++d) acc[qt][d][r] *= corr;
          mrow[qt][r] = mnew;
        }
    }
    // P = exp(s - m) (bounded by e^8), write to padded LDS (no sum reduce)
#pragma unroll
    for (int qt = 0; qt < 2; ++qt) {
#pragma unroll
      for (int r = 0; r < 4; ++r) {
        const float m = mrow[qt][r];
#pragma unroll
        for (int jt = 0; jt < 4; ++jt) {
          float v = s[qt][jt][r];
          float p = (v > -1e29f) ? __expf(v - m) : 0.f;
          p_lds[w][qt][(hi * 4 + r) * 72 + jt * 16 + lo] = __float2bfloat16(p);
        }
      }
    }
    // PV over the 2 k-subtiles of 32; row-sum rides along as ones-MFMA
#pragma unroll
    for (int ks2 = 0; ks2 < 2; ++ks2) {
      b16x8 pa[2];
      pa[0] = *(const b16x8*)((const __bf16*)p_lds[w][0] + lo * 72 + ks2 * 32 + hi * 8);
      pa[1] = *(const b16x8*)((const __bf16*)p_lds[w][1] + lo * 72 + ks2 * 32 + hi * 8);
#pragma unroll
      for (int qt = 0; qt < 2; ++qt) accs[qt] = MFMA16(pa[qt], ONES, accs[qt]);
#pragma unroll
      for (int dh = 0; dh < 2; ++dh) {
        b16x8 bv[4];
#pragma unroll
        for (int dd = 0; dd < 4; ++dd) {
          int d = dh * 4 + dd;
          bv[dd] = *(const b16x8*)(vtp + (size_t)(d * 16 + lo) * CAPN + j0 + ks2 * 32 + hi * 8);
        }
#pragma unroll
        for (int qt = 0; qt < 2; ++qt)
#pragma unroll
          for (int dd = 0; dd < 4; ++dd)
            acc[qt][dh * 4 + dd] = MFMA16(pa[qt], bv[dd], acc[qt][dh * 4 + dd]);
      }
    }
  }
#pragma unroll
  for (int qt = 0; qt < 2; ++qt)
#pragma unroll
    for (int d = 0; d < 8; ++d)
#pragma unroll
      for (int r = 0; r < 4; ++r) {
        int row = i0b + qt * 16 + hi * 4 + r;
        attb[(tb + row) * DIM + h * HDIM + d * 16 + lo] =
            __float2bfloat16(acc[qt][d][r] / accs[qt][r]);
      }
}

// ---------------- scale by top_w and scatter into pred ----------------
__global__ __launch_bounds__(256) void scatter_kernel(const float* __restrict__ lat,
                                                      const int* __restrict__ idxs,
                                                      const float* __restrict__ topw,
                                                      float* __restrict__ pred) {
  int tok = blockIdx.x;
  int b = tok >> 10, i = tok & 1023;
  int dst = idxs[b * CAPN + i];
  float wv = topw[b * CAPN + i];
  const float4* spv = (const float4*)(lat + (size_t)tok * DIM);
  float4* dp = (float4*)(pred + ((size_t)b * SEQ + dst) * DIM);
  int t = threadIdx.x;
  float4 v = spv[t];
  v.x *= wv; v.y *= wv; v.z *= wv; v.w *= wv;
  dp[t] = v;
  v = spv[t + 256];
  v.x *= wv; v.y *= wv; v.z *= wv; v.w *= wv;
  dp[t + 256] = v;
}

extern "C" void kernel_launch(void* const* d_in, const int* in_sizes, int n_in,
                              void* d_out, int out_size, void* d_ws, size_t ws_size,
                              hipStream_t stream) {
  const float* x        = (const float*)d_in[0];
  const float* router_w = (const float*)d_in[1];
  const float* norm1_w  = (const float*)d_in[2];
  const float* norm2_w  = (const float*)d_in[3];
  const float* qkv_w    = (const float*)d_in[4];
  const float* proj_w   = (const float*)d_in[5];
  const float* fc1_w    = (const float*)d_in[6];
  const float* fc2_w    = (const float*)d_in[7];

  float* pred   = (float*)d_out;                       // [NB,SEQ,DIM]
  float* rw_out = pred + (size_t)NB * SEQ * DIM;       // [NB,SEQ,1]
  float* dec    = rw_out + (size_t)NB * SEQ;           // [NB,SEQ,1]

  // workspace
  char* ws = (char*)d_ws;
  float* lat  = (float*)ws; ws += (size_t)MTOK * DIM * 4;       // 33.5 MB f32
  bf16* xn    = (bf16*)ws;  ws += (size_t)MTOK * DIM * 2;       // 16.8 MB
  bf16* qkvb  = (bf16*)ws;  ws += (size_t)MTOK * QKVN * 2;      // 25.2 MB
  bf16* attb  = (bf16*)ws;  ws += (size_t)MTOK * DIM * 2;       // 16.8 MB
  int* rank   = (int*)ws;   ws += (size_t)NB * SEQ * 4;
  int* idxs   = (int*)ws;   ws += (size_t)NB * CAPN * 4;
  float* topw = (float*)ws; ws += (size_t)NB * CAPN * 4;

  // scratch inside the pred output region (zeroed only at the very end)
  char* sp = (char*)pred;
  sp += (size_t)MTOK * (2 * DIM) * 2;                          // (hole, unused)
  bf16* wq = (bf16*)sp; sp += (size_t)QKVN * DIM * 2;          // 12.6 MB
  bf16* wp = (bf16*)sp; sp += (size_t)DIM * DIM * 2;           //  8.4 MB
  bf16* w1 = (bf16*)sp; sp += (size_t)(2 * DIM) * DIM * 2;     // 16.8 MB
  bf16* w2 = (bf16*)sp; sp += (size_t)DIM * DIM * 2;           //  8.4 MB
  bf16* vT = (bf16*)sp; sp += (size_t)NB * NKVH * HDIM * CAPN * 2;  // 4.2 MB

  // router + top-k (f32 exact path)
  router_kernel<<<NB * SEQ / 4, 256, 0, stream>>>(x, router_w, rw_out);
  hipMemsetAsync(rank, 0, (size_t)NB * SEQ * 4, stream);
  rankcnt_kernel<<<NB * 256, 256, 0, stream>>>(rw_out, rank);
  select_kernel<<<NB, 1024, 0, stream>>>(rank, rw_out, idxs, topw, dec);
  gather_kernel<<<MTOK, 256, 0, stream>>>(x, idxs, lat);

  for (int l = 0; l < NLAYER; ++l) {
    cast_kernel<<<(QKVN * DIM) / 1024, 256, 0, stream>>>(qkv_w + (size_t)l * QKVN * DIM, wq, QKVN * DIM);
    cast_kernel<<<(DIM * DIM) / 1024, 256, 0, stream>>>(proj_w + (size_t)l * DIM * DIM, wp, DIM * DIM);
    cast_fc1_kernel<<<2 * DIM, 256, 0, stream>>>(fc1_w + (size_t)l * 2 * DIM * DIM, w1);
    cast_kernel<<<(DIM * DIM) / 1024, 256, 0, stream>>>(fc2_w + (size_t)l * DIM * DIM, w2, DIM * DIM);

    rmsnorm_kernel<<<MTOK, 256, 0, stream>>>(lat, norm1_w + (size_t)l * DIM, xn);
    // qkv: M=4096 N=3072 -> grid 32*24 = 768
    gemm97<1><<<(MTOK / 128) * (QKVN / 128), 256, 0, stream>>>(
        xn, wq, nullptr, qkvb, vT, QKVN, DIM, QKVN / 128);
    attn_kernel<<<NB * NKVH * 32, 256, 0, stream>>>(qkvb, vT, attb);
    // proj: residual add into lat, grid 32*16 = 512
    gemm97<3><<<(MTOK / 128) * (DIM / 128), 256, 0, stream>>>(
        attb, wp, lat, nullptr, nullptr, DIM, DIM, DIM / 128);

    rmsnorm_kernel<<<MTOK, 256, 0, stream>>>(lat, norm2_w + (size_t)l * DIM, xn);
    // fc1 + fused SwiGLU: grid 32*32 = 1024, out attb [4096,2048]
    gemm97<2><<<(MTOK / 128) * (2 * DIM / 128), 256, 0, stream>>>(
        xn, w1, nullptr, attb, nullptr, 2 * DIM, DIM, 2 * DIM / 128);
    // fc2: residual add into lat, grid 512
    gemm97<3><<<(MTOK / 128) * (DIM / 128), 256, 0, stream>>>(
        attb, w2, lat, nullptr, nullptr, DIM, DIM, DIM / 128);
  }

  // finalize outputs: zero pred (erases scratch), then scatter lat * top_w
  hipMemsetAsync(pred, 0, (size_t)NB * SEQ * DIM * 4, stream);
  scatter_kernel<<<MTOK, 256, 0, stream>>>(lat, idxs, topw, pred);
}

// Round 13
// 1479.419 us; speedup vs baseline: 1.1575x; 1.0138x over previous
//
#include <hip/hip_runtime.h>
#include <hip/hip_bf16.h>

constexpr int NB = 4;
constexpr int SEQ = 4096;
constexpr int DIM = 2048;
constexpr int NLAYER = 4;
constexpr int NQH = 16;
constexpr int NKVH = 4;
constexpr int WIN = 512;
constexpr int HDIM = 128;
constexpr int CAPN = 1024;
constexpr int MTOK = NB * CAPN;                 // 4096 latent tokens
constexpr int QKVN = (NQH + 2 * NKVH) * HDIM;  // 3072
constexpr int VOFF = DIM + NKVH * HDIM;        // 2560, start of V cols
constexpr float EPSF = 1.1920928955078125e-07f;

// merged-cast region boundaries (f32 element counts)
constexpr int CQKV = QKVN * DIM;              //  6291456
constexpr int CPROJ = CQKV + DIM * DIM;       // 10485760
constexpr int CFC1 = CPROJ + 2 * DIM * DIM;   // 18874368
constexpr int CALL = CFC1 + DIM * DIM;        // 23068672

typedef __hip_bfloat16 bf16;
typedef __bf16 b16x8 __attribute__((ext_vector_type(8)));
typedef __bf16 b16x4 __attribute__((ext_vector_type(4)));
typedef float f32x4 __attribute__((ext_vector_type(4)));

#define MFMA16(a, b, c) __builtin_amdgcn_mfma_f32_16x16x32_bf16((a), (b), (c), 0, 0, 0)

__device__ __forceinline__ void gload_lds16(const void* g, void* l) {
  __builtin_amdgcn_global_load_lds((__attribute__((address_space(1))) void*)(void*)g,
                                   (__attribute__((address_space(3))) void*)l, 16, 0, 0);
}

// ------- merged weight cast for one layer: qkv | proj | fc1(interleaved) | fc2 -------
// fc1 row interleave: phys row p -> logical L = (p&31)<16 ? (p>>5)*16+(p&31)
//                                             : DIM + (p>>5)*16 + (p&31) - 16
__global__ __launch_bounds__(256) void cast_all_kernel(const float* __restrict__ qkvw,
                                                       const float* __restrict__ projw,
                                                       const float* __restrict__ fc1w,
                                                       const float* __restrict__ fc2w,
                                                       bf16* __restrict__ wq,
                                                       bf16* __restrict__ wp,
                                                       bf16* __restrict__ w1,
                                                       bf16* __restrict__ w2) {
  int idx = (blockIdx.x * 256 + threadIdx.x) * 4;
  if (idx >= CALL) return;
  const float* src;
  __bf16* dst;
  if (idx < CQKV) {
    src = qkvw + idx;
    dst = (__bf16*)wq + idx;
  } else if (idx < CPROJ) {
    int o = idx - CQKV;
    src = projw + o;
    dst = (__bf16*)wp + o;
  } else if (idx < CFC1) {
    int o = idx - CPROJ;
    int p = o / DIM, col = o - p * DIM;
    int w = p & 31, chunk = p >> 5;
    int L = (w < 16) ? (chunk * 16 + w) : (DIM + chunk * 16 + (w - 16));
    src = fc1w + (size_t)L * DIM + col;
    dst = (__bf16*)w1 + o;
  } else {
    int o = idx - CFC1;
    src = fc2w + o;
    dst = (__bf16*)w2 + o;
  }
  float4 v = *(const float4*)src;
  b16x4 ov;
  ov[0] = (__bf16)v.x; ov[1] = (__bf16)v.y; ov[2] = (__bf16)v.z; ov[3] = (__bf16)v.w;
  *(b16x4*)dst = ov;
}

// ---------------- router: rw = sigmoid(x @ w^T), all f32 ----------------
__global__ __launch_bounds__(256) void router_kernel(const float* __restrict__ x,
                                                     const float* __restrict__ rwt,
                                                     float* __restrict__ rw_out) {
  int tok = blockIdx.x * 4 + (threadIdx.x >> 6);
  int l = threadIdx.x & 63;
  const float* xr = x + (size_t)tok * DIM;
  float s = 0.f;
  for (int c = l; c < DIM; c += 64) s += xr[c] * rwt[c];
  for (int off = 32; off; off >>= 1) s += __shfl_down(s, off);
  if (l == 0) rw_out[tok] = 1.f / (1.f + expf(-s));
}

// ------- rank count, tiled: block (b, jc, ic) counts chunk-vs-chunk -------
__global__ __launch_bounds__(256) void rankcnt_kernel(const float* __restrict__ rw,
                                                      int* __restrict__ rank) {
  int blk = blockIdx.x;
  int ic = blk & 15, jc = (blk >> 4) & 15, b = blk >> 8;
  __shared__ float4 svi[64];
  int t = threadIdx.x;
  if (t < 64) svi[t] = ((const float4*)(rw + (size_t)b * SEQ + ic * 256))[t];
  __syncthreads();
  int j = jc * 256 + t;
  float vj = rw[(size_t)b * SEQ + j];
  int r = 0;
#pragma unroll 16
  for (int q = 0; q < 64; ++q) {
    float4 v = svi[q];
    int i = ic * 256 + q * 4;
    r += (v.x > vj || (v.x == vj && (i + 0) < j)) ? 1 : 0;
    r += (v.y > vj || (v.y == vj && (i + 1) < j)) ? 1 : 0;
    r += (v.z > vj || (v.z == vj && (i + 2) < j)) ? 1 : 0;
    r += (v.w > vj || (v.w == vj && (i + 3) < j)) ? 1 : 0;
  }
  atomicAdd(&rank[b * SEQ + j], r);
}

// -------- select: compact ascending-index selected; top_w quirk gather;
// writes `decisions` and the inverse map srcmap[b,j] = compact idx or -1 --------
__global__ __launch_bounds__(1024) void select_kernel(const int* __restrict__ rank,
                                                      const float* __restrict__ rw,
                                                      int* __restrict__ idxs,
                                                      float* __restrict__ topw,
                                                      float* __restrict__ dec,
                                                      int* __restrict__ srcmap) {
  int b = blockIdx.x;
  int t = threadIdx.x;
  __shared__ int sr[SEQ];
  __shared__ int scnt[1024];
  for (int i = t; i < SEQ; i += 1024) sr[i] = rank[b * SEQ + i];
  __syncthreads();
  for (int i = t; i < SEQ; i += 1024) dec[(size_t)b * SEQ + i] = (sr[i] < CAPN) ? 1.0f : 0.0f;
  int c = 0;
#pragma unroll
  for (int k = 0; k < 4; ++k) c += (sr[t * 4 + k] < CAPN) ? 1 : 0;
  scnt[t] = c;
  __syncthreads();
  for (int off = 1; off < 1024; off <<= 1) {
    int v = scnt[t];
    int vm = (t >= off) ? scnt[t - off] : 0;
    __syncthreads();
    scnt[t] = v + vm;
    __syncthreads();
  }
  int pos = scnt[t] - c;  // exclusive prefix
  for (int k = 0; k < 4; ++k) {
    int j = t * 4 + k;
    int r = sr[j];
    if (r < CAPN) {
      idxs[b * CAPN + pos] = j;
      topw[b * CAPN + pos] = rw[(size_t)b * SEQ + r];
      srcmap[b * SEQ + j] = pos;
      pos++;
    } else {
      srcmap[b * SEQ + j] = -1;
    }
  }
}

// ---------------- gather selected rows ----------------
__global__ __launch_bounds__(256) void gather_kernel(const float* __restrict__ x,
                                                     const int* __restrict__ idxs,
                                                     float* __restrict__ lat) {
  int tok = blockIdx.x;
  int b = tok >> 10, i = tok & 1023;
  int src = idxs[b * CAPN + i];
  const float4* spv = (const float4*)(x + ((size_t)b * SEQ + src) * DIM);
  float4* dp = (float4*)(lat + (size_t)tok * DIM);
  int t = threadIdx.x;
  dp[t] = spv[t];
  dp[t + 256] = spv[t + 256];
}

// ---------------- RMSNorm (f32 in, bf16 out) ----------------
__global__ __launch_bounds__(256) void rmsnorm_kernel(const float* __restrict__ in,
                                                      const float* __restrict__ w,
                                                      bf16* __restrict__ out) {
  int row = blockIdx.x;
  int t = threadIdx.x;
  const float4* spv = (const float4*)(in + (size_t)row * DIM);
  float4 v0 = spv[t], v1 = spv[t + 256];
  float ss = v0.x * v0.x + v0.y * v0.y + v0.z * v0.z + v0.w * v0.w +
             v1.x * v1.x + v1.y * v1.y + v1.z * v1.z + v1.w * v1.w;
  for (int off = 32; off; off >>= 1) ss += __shfl_down(ss, off);
  __shared__ float red[4];
  if ((t & 63) == 0) red[t >> 6] = ss;
  __syncthreads();
  float total = red[0] + red[1] + red[2] + red[3];
  float sc = rsqrtf(total * (1.0f / DIM) + EPSF);
  const float4* wp = (const float4*)w;
  float4 w0 = wp[t], w1 = wp[t + 256];
  __bf16* op = (__bf16*)out + (size_t)row * DIM;
  b16x4 o0, o1;
  o0[0] = (__bf16)(v0.x * w0.x * sc); o0[1] = (__bf16)(v0.y * w0.y * sc);
  o0[2] = (__bf16)(v0.z * w0.z * sc); o0[3] = (__bf16)(v0.w * w0.w * sc);
  o1[0] = (__bf16)(v1.x * w1.x * sc); o1[1] = (__bf16)(v1.y * w1.y * sc);
  o1[2] = (__bf16)(v1.z * w1.z * sc); o1[3] = (__bf16)(v1.w * w1.w * sc);
  *(b16x4*)(op + t * 4) = o0;
  *(b16x4*)(op + 1024 + t * 4) = o1;
}

// ============ m97-structure GEMM: 128x128 tile, BK=64, single-buffer ============
// 256 thr (4 waves 2x2), LDS 32 KB -> 3 blocks/CU. Mechanism: CROSS-BLOCK
// overlap (m114). MODE: 1 = bf16 + vT side-write; 2 = fused SwiGLU; 3 = f32 add.

__device__ __forceinline__ void stage97(const bf16* g, int K, int kt,
                                        bf16* tile, int tid) {
#pragma unroll
  for (int j = 0; j < 4; ++j) {
    int q = j * 4096 + tid * 16;
    int row = q >> 7;
    int sc = ((tid & 7) ^ (row & 7)) << 3;
    gload_lds16((const __bf16*)g + (size_t)row * K + kt * 64 + sc,
                (char*)tile + q);
  }
}

__device__ __forceinline__ b16x8 frag97(const bf16* buf, int row, int ks, int hi) {
  int co = (ks * 32 + hi * 8) ^ ((row & 7) << 3);
  return *(const b16x8*)((const __bf16*)buf + row * 64 + co);
}

template <int MODE>
__global__ __launch_bounds__(256, 3) void gemm97(const bf16* __restrict__ A,
                                                 const bf16* __restrict__ Bw,
                                                 float* __restrict__ Cf,
                                                 bf16* __restrict__ Cb,
                                                 bf16* __restrict__ vTout,
                                                 int N, int K, int nbn) {
  __shared__ __align__(16) bf16 sA[128 * 64];
  __shared__ __align__(16) bf16 sB[128 * 64];
  const int tid = threadIdx.x;
  const int w = tid >> 6, l = tid & 63;
  const int lo = l & 15, hi = l >> 4;
  const int wr = w >> 1, wc = w & 1;
  const int nwg = gridDim.x;
  int bid = blockIdx.x;
  bid = (bid & 7) * (nwg >> 3) + (bid >> 3);  // T1 XCD swizzle (nwg%8==0)
  const int bm = bid / nbn, bn = bid % nbn;
  const bf16* Ab = A + (size_t)bm * 128 * K;
  const bf16* Bb = Bw + (size_t)bn * 128 * K;
  const int nt = K >> 6;

  f32x4 acc[4][4];
#pragma unroll
  for (int i = 0; i < 4; ++i)
#pragma unroll
    for (int j = 0; j < 4; ++j) acc[i][j] = f32x4{0.f, 0.f, 0.f, 0.f};

  for (int t = 0; t < nt; ++t) {
    stage97(Ab, K, t, sA, tid);
    stage97(Bb, K, t, sB, tid);
    __syncthreads();
#pragma unroll
    for (int ks = 0; ks < 2; ++ks) {
      b16x8 af[4], bfm[4];
#pragma unroll
      for (int mi = 0; mi < 4; ++mi)
        af[mi] = frag97(sA, wr * 64 + mi * 16 + lo, ks, hi);
#pragma unroll
      for (int ni = 0; ni < 4; ++ni)
        bfm[ni] = frag97(sB, wc * 64 + ni * 16 + lo, ks, hi);
#pragma unroll
      for (int mi = 0; mi < 4; ++mi)
#pragma unroll
        for (int ni = 0; ni < 4; ++ni)
          acc[mi][ni] = MFMA16(af[mi], bfm[ni], acc[mi][ni]);
    }
    __syncthreads();
  }

  // epilogue
#pragma unroll
  for (int mi = 0; mi < 4; ++mi) {
    int row0 = bm * 128 + wr * 64 + mi * 16 + hi * 4;
    if constexpr (MODE == 2) {
#pragma unroll
      for (int j2 = 0; j2 < 2; ++j2) {
        int colL = bn * 64 + wc * 32 + j2 * 16 + lo;
#pragma unroll
        for (int r = 0; r < 4; ++r) {
          float a = acc[mi][2 * j2][r];
          float g = acc[mi][2 * j2 + 1][r];
          float s = g / (1.f + __expf(-g));
          Cb[(size_t)(row0 + r) * DIM + colL] = __float2bfloat16(a * s);
        }
      }
    } else {
#pragma unroll
      for (int ni = 0; ni < 4; ++ni) {
        int col = bn * 128 + wc * 64 + ni * 16 + lo;
#pragma unroll
        for (int r = 0; r < 4; ++r) {
          size_t idx = (size_t)(row0 + r) * N + col;
          float v = acc[mi][ni][r];
          if constexpr (MODE == 3) {
            Cf[idx] += v;
          } else {
            bf16 bv = __float2bfloat16(v);
            Cb[idx] = bv;
            if constexpr (MODE == 1) {
              if (col >= VOFF) {
                int cc = col - VOFF;
                int kvh = cc >> 7, d = cc & 127;
                int row = row0 + r;
                int bb = row >> 10, tk = row & 1023;
                vTout[((size_t)(bb * NKVH + kvh) * HDIM + d) * CAPN + tk] = bv;
              }
            }
          }
        }
      }
    }
  }
}

// ------------- GQA attention (R9/R12 structure, at its measured plateau):
// 32-row q-chunks, direct-global K (L1-hot), 64-col K-steps, diag-first order,
// defer-max via per-lane compare + __any, row-sum via ones-MFMA. -------------
__global__ __launch_bounds__(256) void attn_kernel(const bf16* __restrict__ qkvb,
                                                   const bf16* __restrict__ vT,
                                                   bf16* __restrict__ attb) {
  const int blk = blockIdx.x;
  const int qc = blk & 31;
  const int kvh = (blk >> 5) & 3;
  const int b = blk >> 7;
  const int w = threadIdx.x >> 6, l = threadIdx.x & 63;
  const int lo = l & 15, hi = l >> 4;
  const int h = kvh * 4 + w;
  const float slope = exp2f(-0.5f * (float)(h + 1));
  const float scale = 0.08838834764831845f;  // 1/sqrt(128)
  __shared__ __align__(16) bf16 p_lds[4][2][16 * 72];  // stride 72 elems (144 B)
  const __bf16* qp = (const __bf16*)qkvb;
  const __bf16* vtp = (const __bf16*)vT + (size_t)(b * NKVH + kvh) * HDIM * CAPN;
  const size_t tb = (size_t)b * CAPN;
  const int i0b = qc * 32;

  b16x8 aq[2][4];
#pragma unroll
  for (int qt = 0; qt < 2; ++qt) {
    const __bf16* qrow = qp + (tb + i0b + qt * 16 + lo) * QKVN + h * HDIM + hi * 8;
#pragma unroll
    for (int c = 0; c < 4; ++c) aq[qt][c] = *(const b16x8*)(qrow + c * 32);
  }

  b16x8 ONES;
#pragma unroll
  for (int j = 0; j < 8; ++j) ONES[j] = (__bf16)1.0f;

  f32x4 acc[2][8];
  f32x4 accs[2];  // row-sum accumulators (via ones-MFMA)
#pragma unroll
  for (int qt = 0; qt < 2; ++qt) {
#pragma unroll
    for (int d = 0; d < 8; ++d) acc[qt][d] = f32x4{0.f, 0.f, 0.f, 0.f};
    accs[qt] = f32x4{0.f, 0.f, 0.f, 0.f};
  }
  float mrow[2][4];
#pragma unroll
  for (int qt = 0; qt < 2; ++qt)
#pragma unroll
    for (int r = 0; r < 4; ++r) mrow[qt][r] = -1e30f;

  const int Ttile = (i0b + 31) & ~63;
  int Btile = i0b - WIN;
  if (Btile < 0) Btile = 0;
  Btile &= ~63;

  for (int j0 = Ttile; j0 >= Btile; j0 -= 64) {
    f32x4 s[2][4];
#pragma unroll
    for (int jtp = 0; jtp < 2; ++jtp) {
      b16x8 kf[2][4];
#pragma unroll
      for (int jt2 = 0; jt2 < 2; ++jt2) {
        const __bf16* krow =
            qp + (tb + j0 + (jtp * 2 + jt2) * 16 + lo) * QKVN + DIM + kvh * HDIM + hi * 8;
#pragma unroll
        for (int c = 0; c < 4; ++c) kf[jt2][c] = *(const b16x8*)(krow + c * 32);
      }
#pragma unroll
      for (int qt = 0; qt < 2; ++qt)
#pragma unroll
        for (int jt2 = 0; jt2 < 2; ++jt2) {
          f32x4 sv = f32x4{0.f, 0.f, 0.f, 0.f};
#pragma unroll
          for (int c = 0; c < 4; ++c) sv = MFMA16(aq[qt][c], kf[jt2][c], sv);
          s[qt][jtp * 2 + jt2] = sv;
        }
    }
    int flag = 0;
#pragma unroll
    for (int qt = 0; qt < 2; ++qt) {
#pragma unroll
      for (int r = 0; r < 4; ++r) {
        const int i = i0b + qt * 16 + hi * 4 + r;
        const float thr = mrow[qt][r] + 8.0f;
#pragma unroll
        for (int jt = 0; jt < 4; ++jt) {
          int d = i - (j0 + jt * 16 + lo);
          float v = (d >= 0 && d <= 512) ? (s[qt][jt][r] * scale - slope * (float)d)
                                         : -1e30f;
          s[qt][jt][r] = v;
          flag |= (v > thr) ? 1 : 0;
        }
      }
    }
    if (__any(flag)) {
#pragma unroll
      for (int qt = 0; qt < 2; ++qt)
#pragma unroll
        for (int r = 0; r < 4; ++r) {
          float tm = -1e30f;
#pragma unroll
          for (int jt = 0; jt < 4; ++jt) tm = fmaxf(tm, s[qt][jt][r]);
#pragma unroll
          for (int off = 1; off < 16; off <<= 1) tm = fmaxf(tm, __shfl_xor(tm, off));
          float mnew = fmaxf(mrow[qt][r], tm);
          float corr = (mrow[qt][r] > -1e29f) ? __expf(mrow[qt][r] - mnew) : 0.f;
          accs[qt][r] *= corr;
#pragma unroll
          for (int d = 0; d < 8; ++d) acc[qt][d][r] *= corr;
          mrow[qt][r] = mnew;
        }
    }
#pragma unroll
    for (int qt = 0; qt < 2; ++qt) {
#pragma unroll
      for (int r = 0; r < 4; ++r) {
        const float m = mrow[qt][r];
#pragma unroll
        for (int jt = 0; jt < 4; ++jt) {
          float v = s[qt][jt][r];
          float p = (v > -1e29f) ? __expf(v - m) : 0.f;
          p_lds[w][qt][(hi * 4 + r) * 72 + jt * 16 + lo] = __float2bfloat16(p);
        }
      }
    }
#pragma unroll
    for (int ks2 = 0; ks2 < 2; ++ks2) {
      b16x8 pa[2];
      pa[0] = *(const b16x8*)((const __bf16*)p_lds[w][0] + lo * 72 + ks2 * 32 + hi * 8);
      pa[1] = *(const b16x8*)((const __bf16*)p_lds[w][1] + lo * 72 + ks2 * 32 + hi * 8);
#pragma unroll
      for (int qt = 0; qt < 2; ++qt) accs[qt] = MFMA16(pa[qt], ONES, accs[qt]);
#pragma unroll
      for (int dh = 0; dh < 2; ++dh) {
        b16x8 bv[4];
#pragma unroll
        for (int dd = 0; dd < 4; ++dd) {
          int d = dh * 4 + dd;
          bv[dd] = *(const b16x8*)(vtp + (size_t)(d * 16 + lo) * CAPN + j0 + ks2 * 32 + hi * 8);
        }
#pragma unroll
        for (int qt = 0; qt < 2; ++qt)
#pragma unroll
          for (int dd = 0; dd < 4; ++dd)
            acc[qt][dh * 4 + dd] = MFMA16(pa[qt], bv[dd], acc[qt][dh * 4 + dd]);
      }
    }
  }
#pragma unroll
  for (int qt = 0; qt < 2; ++qt)
#pragma unroll
    for (int d = 0; d < 8; ++d)
#pragma unroll
      for (int r = 0; r < 4; ++r) {
        int row = i0b + qt * 16 + hi * 4 + r;
        attb[(tb + row) * DIM + h * HDIM + d * 16 + lo] =
            __float2bfloat16(acc[qt][d][r] / accs[qt][r]);
      }
}

// ---- final pred writer: every row gets lat*topw (selected) or zeros ----
// Replaces memset(134MB)+scatter: one pass, overwrites all scratch in pred.
__global__ __launch_bounds__(256) void pred_write_kernel(const float* __restrict__ lat,
                                                         const int* __restrict__ srcmap,
                                                         const float* __restrict__ topw,
                                                         float* __restrict__ pred) {
  int row = blockIdx.x;           // [0, NB*SEQ)
  int b = row >> 12;              // SEQ = 4096
  int i = srcmap[row];
  int t = threadIdx.x;
  float4* dp = (float4*)(pred + (size_t)row * DIM);
  if (i >= 0) {
    float wv = topw[b * CAPN + i];
    const float4* spv = (const float4*)(lat + ((size_t)b * CAPN + i) * DIM);
    float4 v = spv[t];
    v.x *= wv; v.y *= wv; v.z *= wv; v.w *= wv;
    dp[t] = v;
    v = spv[t + 256];
    v.x *= wv; v.y *= wv; v.z *= wv; v.w *= wv;
    dp[t + 256] = v;
  } else {
    float4 z = {0.f, 0.f, 0.f, 0.f};
    dp[t] = z;
    dp[t + 256] = z;
  }
}

extern "C" void kernel_launch(void* const* d_in, const int* in_sizes, int n_in,
                              void* d_out, int out_size, void* d_ws, size_t ws_size,
                              hipStream_t stream) {
  const float* x        = (const float*)d_in[0];
  const float* router_w = (const float*)d_in[1];
  const float* norm1_w  = (const float*)d_in[2];
  const float* norm2_w  = (const float*)d_in[3];
  const float* qkv_w    = (const float*)d_in[4];
  const float* proj_w   = (const float*)d_in[5];
  const float* fc1_w    = (const float*)d_in[6];
  const float* fc2_w    = (const float*)d_in[7];

  float* pred   = (float*)d_out;                       // [NB,SEQ,DIM]
  float* rw_out = pred + (size_t)NB * SEQ * DIM;       // [NB,SEQ,1]
  float* dec    = rw_out + (size_t)NB * SEQ;           // [NB,SEQ,1]

  // workspace
  char* ws = (char*)d_ws;
  float* lat  = (float*)ws; ws += (size_t)MTOK * DIM * 4;       // 33.5 MB f32
  bf16* xn    = (bf16*)ws;  ws += (size_t)MTOK * DIM * 2;       // 16.8 MB
  bf16* qkvb  = (bf16*)ws;  ws += (size_t)MTOK * QKVN * 2;      // 25.2 MB
  bf16* attb  = (bf16*)ws;  ws += (size_t)MTOK * DIM * 2;       // 16.8 MB
  int* rank   = (int*)ws;   ws += (size_t)NB * SEQ * 4;
  int* idxs   = (int*)ws;   ws += (size_t)NB * CAPN * 4;
  float* topw = (float*)ws; ws += (size_t)NB * CAPN * 4;
  int* srcmap = (int*)ws;   ws += (size_t)NB * SEQ * 4;

  // scratch inside the pred output region (overwritten by pred_write at end)
  char* sp = (char*)pred;
  sp += (size_t)MTOK * (2 * DIM) * 2;                          // (hole, unused)
  bf16* wq = (bf16*)sp; sp += (size_t)QKVN * DIM * 2;          // 12.6 MB
  bf16* wp = (bf16*)sp; sp += (size_t)DIM * DIM * 2;           //  8.4 MB
  bf16* w1 = (bf16*)sp; sp += (size_t)(2 * DIM) * DIM * 2;     // 16.8 MB
  bf16* w2 = (bf16*)sp; sp += (size_t)DIM * DIM * 2;           //  8.4 MB
  bf16* vT = (bf16*)sp; sp += (size_t)NB * NKVH * HDIM * CAPN * 2;  // 4.2 MB

  // router + top-k (f32 exact path)
  router_kernel<<<NB * SEQ / 4, 256, 0, stream>>>(x, router_w, rw_out);
  hipMemsetAsync(rank, 0, (size_t)NB * SEQ * 4, stream);
  rankcnt_kernel<<<NB * 256, 256, 0, stream>>>(rw_out, rank);
  select_kernel<<<NB, 1024, 0, stream>>>(rank, rw_out, idxs, topw, dec, srcmap);
  gather_kernel<<<MTOK, 256, 0, stream>>>(x, idxs, lat);

  for (int l = 0; l < NLAYER; ++l) {
    cast_all_kernel<<<(CALL + 1023) / 1024, 256, 0, stream>>>(
        qkv_w + (size_t)l * CQKV, proj_w + (size_t)l * DIM * DIM,
        fc1_w + (size_t)l * 2 * DIM * DIM, fc2_w + (size_t)l * DIM * DIM,
        wq, wp, w1, w2);

    rmsnorm_kernel<<<MTOK, 256, 0, stream>>>(lat, norm1_w + (size_t)l * DIM, xn);
    // qkv: M=4096 N=3072 -> grid 32*24 = 768
    gemm97<1><<<(MTOK / 128) * (QKVN / 128), 256, 0, stream>>>(
        xn, wq, nullptr, qkvb, vT, QKVN, DIM, QKVN / 128);
    attn_kernel<<<NB * NKVH * 32, 256, 0, stream>>>(qkvb, vT, attb);
    // proj: residual add into lat, grid 32*16 = 512
    gemm97<3><<<(MTOK / 128) * (DIM / 128), 256, 0, stream>>>(
        attb, wp, lat, nullptr, nullptr, DIM, DIM, DIM / 128);

    rmsnorm_kernel<<<MTOK, 256, 0, stream>>>(lat, norm2_w + (size_t)l * DIM, xn);
    // fc1 + fused SwiGLU: grid 32*32 = 1024, out attb [4096,2048]
    gemm97<2><<<(MTOK / 128) * (2 * DIM / 128), 256, 0, stream>>>(
        xn, w1, nullptr, attb, nullptr, 2 * DIM, DIM, 2 * DIM / 128);
    // fc2: residual add into lat, grid 512
    gemm97<3><<<(MTOK / 128) * (DIM / 128), 256, 0, stream>>>(
        attb, w2, lat, nullptr, nullptr, DIM, DIM, DIM / 128);
  }

  // finalize: one pass writes all of pred (zeros or lat*topw), erasing scratch
  pred_write_kernel<<<NB * SEQ, 256, 0, stream>>>(lat, srcmap, topw, pred);
}